// Round 4
// baseline (2147.973 us; speedup 1.0000x reference)
//
#include <hip/hip_runtime.h>
#include <hip/hip_bf16.h>
#include <math.h>

#define B_SZ 8
#define LSEQ 512
#define DM 768
#define DI 1536
#define DSTATE 16
#define DTRANK 48
#define M_ROWS (B_SZ * LSEQ)   // 4096

// ---------------------------------------------------------------------------
// GEMM: C[M,N](fp32) (+)= A[M,K](fp32) @ W[K,N](fp32) + b1 + b2
// flags: bit0 = accumulate into C, bit1 = softplus epilogue,
//        bit2 = conv mode (K = 8 segments of 768; segment s<7 uses A rows
//               shifted by s-3 within each L=512 batch slice, seg 7 unshifted)
// Tile 64x64x16, 256 threads, 4x4 micro-tile, fp32 accumulate.
// ---------------------------------------------------------------------------
__global__ __launch_bounds__(256) void gemm_k(
    const float* __restrict__ A, int lda,
    const float* __restrict__ W, int ldw,
    const float* __restrict__ b1, const float* __restrict__ b2,
    float* __restrict__ C, int ldc,
    int M, int N, int K, int flags)
{
    __shared__ float As[16][64];   // [k][m]
    __shared__ float Bs[16][64];   // [k][n]
    const int tid = threadIdx.x;
    const int bm = blockIdx.x * 64;
    const int bn = blockIdx.y * 64;
    // A loader: row = tid>>2 (0..63), k-quad = (tid&3)*4
    const int arow = tid >> 2;
    const int akq  = (tid & 3) << 2;
    const int m    = bm + arow;
    const int bidx = m >> 9;
    const int l    = m & 511;
    // B loader: k-row = tid>>4, n-quad = (tid&15)*4
    const int bkr = tid >> 4;
    const int bnq = (tid & 15) << 2;
    // compute thread
    const int tr = tid >> 4;
    const int tc = tid & 15;

    float acc[4][4];
    #pragma unroll
    for (int i = 0; i < 4; i++)
        #pragma unroll
        for (int j = 0; j < 4; j++) acc[i][j] = 0.f;

    for (int k0 = 0; k0 < K; k0 += 16) {
        int koff = k0, sh = 0;
        if (flags & 4) {
            const int seg = k0 / DM;
            koff = k0 - seg * DM;
            sh = (seg < 7) ? (seg - 3) : 0;
        }
        const int ls = l + sh;
        float4 av = make_float4(0.f, 0.f, 0.f, 0.f);
        if (m < M && ls >= 0 && ls < LSEQ)
            av = *(const float4*)(A + (size_t)(bidx * LSEQ + ls) * lda + koff + akq);
        As[akq + 0][arow] = av.x;
        As[akq + 1][arow] = av.y;
        As[akq + 2][arow] = av.z;
        As[akq + 3][arow] = av.w;

        const int ncol = bn + bnq;
        const float* wp = W + (size_t)(k0 + bkr) * ldw + ncol;
        if (ncol + 3 < N) {
            const float4 wv = *(const float4*)wp;
            Bs[bkr][bnq + 0] = wv.x;
            Bs[bkr][bnq + 1] = wv.y;
            Bs[bkr][bnq + 2] = wv.z;
            Bs[bkr][bnq + 3] = wv.w;
        } else {
            #pragma unroll
            for (int j = 0; j < 4; j++)
                Bs[bkr][bnq + j] = (ncol + j < N) ? wp[j] : 0.f;
        }
        __syncthreads();

        #pragma unroll
        for (int kk = 0; kk < 16; kk++) {
            const float4 a = *(const float4*)&As[kk][tr << 2];
            const float4 b = *(const float4*)&Bs[kk][tc << 2];
            acc[0][0] += a.x * b.x; acc[0][1] += a.x * b.y; acc[0][2] += a.x * b.z; acc[0][3] += a.x * b.w;
            acc[1][0] += a.y * b.x; acc[1][1] += a.y * b.y; acc[1][2] += a.y * b.z; acc[1][3] += a.y * b.w;
            acc[2][0] += a.z * b.x; acc[2][1] += a.z * b.y; acc[2][2] += a.z * b.z; acc[2][3] += a.z * b.w;
            acc[3][0] += a.w * b.x; acc[3][1] += a.w * b.y; acc[3][2] += a.w * b.z; acc[3][3] += a.w * b.w;
        }
        __syncthreads();
    }

    #pragma unroll
    for (int i = 0; i < 4; i++) {
        const int row = bm + (tr << 2) + i;
        if (row >= M) continue;
        #pragma unroll
        for (int j = 0; j < 4; j++) {
            const int col = bn + (tc << 2) + j;
            if (col >= N) continue;
            float v = acc[i][j];
            if (b1) v += b1[col];
            if (b2) v += b2[col];
            if (flags & 1) v += C[(size_t)row * ldc + col];
            if (flags & 2) v = (v > 20.f) ? v : log1pf(__expf(v));
            C[(size_t)row * ldc + col] = v;
        }
    }
}

// adj = sigmoid(nv1 @ nv2) * (1 - eye)  -> fp32
__global__ void adj_k(const float* __restrict__ nv1, const float* __restrict__ nv2,
                      float* __restrict__ out)
{
    int t = blockIdx.x * 256 + threadIdx.x;
    if (t >= 64 * 64) return;
    int i = t >> 6, j = t & 63;
    float s = 0.f;
    #pragma unroll
    for (int k = 0; k < 16; k++) s += nv1[i * 16 + k] * nv2[k * 64 + j];
    out[t] = (i == j) ? 0.f : 1.f / (1.f + __expf(-s));
}

// LayerNorm over last dim (768): outf = LN(xin (+ addf)) * w + b, all fp32
__global__ __launch_bounds__(256) void ln_k(
    const float* __restrict__ xin, const float* __restrict__ addf,
    const float* __restrict__ w, const float* __restrict__ bparam,
    float* __restrict__ outf)
{
    const int r = blockIdx.x;
    const int tid = threadIdx.x;
    const size_t base = (size_t)r * DM;
    float v[3];
    float s = 0.f, ss = 0.f;
    #pragma unroll
    for (int j = 0; j < 3; j++) {
        const int c = tid + 256 * j;
        float vv = xin[base + c];
        if (addf) vv += addf[base + c];
        v[j] = vv; s += vv; ss += vv * vv;
    }
    #pragma unroll
    for (int o = 32; o > 0; o >>= 1) { s += __shfl_down(s, o); ss += __shfl_down(ss, o); }
    __shared__ float sw[4], ssw[4];
    __shared__ float mu_s, rs_s;
    const int wid = tid >> 6;
    if ((tid & 63) == 0) { sw[wid] = s; ssw[wid] = ss; }
    __syncthreads();
    if (tid == 0) {
        float st = 0.f, sst = 0.f;
        #pragma unroll
        for (int i = 0; i < 4; i++) { st += sw[i]; sst += ssw[i]; }
        const float mu = st / (float)DM;
        const float var = sst / (float)DM - mu * mu;
        mu_s = mu; rs_s = rsqrtf(fmaxf(var, 0.f) + 1e-5f);
    }
    __syncthreads();
    const float mu = mu_s, rs = rs_s;
    #pragma unroll
    for (int j = 0; j < 3; j++) {
        const int c = tid + 256 * j;
        outf[base + c] = (v[j] - mu) * rs * w[c] + bparam[c];
    }
}

// build wcat[8*768,768]: slices 0..6 = conv_w (o,i,k) -> [k][i][o]; slice 7 = gcn_w
__global__ void wcat_k(const float* __restrict__ cw, const float* __restrict__ gw,
                       float* __restrict__ wcat)
{
    int t = blockIdx.x * 256 + threadIdx.x;
    if (t >= 8 * DM * DM) return;
    const int k = t / (DM * DM);
    if (k < 7) {
        const int o = t % DM;
        const int i = (t / DM) % DM;
        wcat[t] = cw[(size_t)o * (DM * 7) + i * 7 + k];
    } else {
        wcat[t] = gw[t - 7 * DM * DM];
    }
}

// depthwise causal conv (D_CONV=4) + bias + silu. xm_raw layout (B*L, DI).
__global__ void dwconv_silu_k(const float* __restrict__ xm_raw, const float* __restrict__ w,
                              const float* __restrict__ bcv, float* __restrict__ out)
{
    int t = blockIdx.x * 256 + threadIdx.x;
    if (t >= M_ROWS * DI) return;
    const int d = t % DI;
    const int bl = t / DI;
    const int l = bl % LSEQ;
    const float* xp = xm_raw + (size_t)bl * DI + d;
    float s = bcv[d];
    #pragma unroll
    for (int k = 0; k < 4; k++) {
        const int ls = l + k - 3;
        if (ls >= 0) s += w[d * 4 + k] * xp[(ptrdiff_t)(k - 3) * DI];
    }
    out[t] = s / (1.f + __expf(-s));
}

// selective scan: 16 lanes per (b,d), state dim in lanes, shfl reduction.
// Writes y IN PLACE over xmc (in-wave read precedes write each step).
__global__ __launch_bounds__(256) void scan_k(
    const float* __restrict__ dtb, float* __restrict__ xmc,
    const float* __restrict__ xdbl, const float* __restrict__ z,
    const float* __restrict__ A_log, const float* __restrict__ Dp)
{
    const int t = blockIdx.x * 256 + threadIdx.x;
    const int lane = t & 15;
    const int g = t >> 4;
    if (g >= B_SZ * DI) return;
    const int d = g % DI;
    const int b = g / DI;
    const float Ad = -__expf(A_log[d * DSTATE + lane]);
    const float Dd = Dp[d];
    float h = 0.f;
    const float* dtp = dtb + (size_t)b * LSEQ * DI + d;
    float*       xp  = xmc + (size_t)b * LSEQ * DI + d;
    const float* bp  = xdbl + (size_t)b * LSEQ * 80 + DTRANK + lane;
    const float* cp  = bp + DSTATE;
    const float* zp  = z + (size_t)b * LSEQ * DI + d;
    for (int l = 0; l < LSEQ; ++l) {
        const float dtv = dtp[(size_t)l * DI];
        const float xv  = xp[(size_t)l * DI];
        const float Bv  = bp[(size_t)l * 80];
        const float Cv  = cp[(size_t)l * 80];
        h = __expf(dtv * Ad) * h + dtv * Bv * xv;
        float p = h * Cv;
        p += __shfl_xor(p, 1);
        p += __shfl_xor(p, 2);
        p += __shfl_xor(p, 4);
        p += __shfl_xor(p, 8);
        if (lane == 0) {
            const float zv = zp[(size_t)l * DI];
            const float sz = zv / (1.f + __expf(-zv));
            xp[(size_t)l * DI] = (p + Dd * xv) * sz;
        }
    }
}

// fused = sigmoid(gb) * xg + (1-sigmoid) * xm  (in-place over gb is safe)
__global__ void fuse_k(const float* __restrict__ gb, const float* __restrict__ xg,
                       const float* __restrict__ xm, float* __restrict__ fused)
{
    int t = blockIdx.x * 256 + threadIdx.x;
    if (t >= M_ROWS * DM) return;
    const float g = 1.f / (1.f + __expf(-gb[t]));
    fused[t] = g * xg[t] + (1.f - g) * xm[t];
}

extern "C" void kernel_launch(void* const* d_in, const int* in_sizes, int n_in,
                              void* d_out, int out_size, void* d_ws, size_t ws_size,
                              hipStream_t stream)
{
    const float* x        = (const float*)d_in[0];
    const float* nv1      = (const float*)d_in[1];
    const float* nv2      = (const float*)d_in[2];
    const float* n1w      = (const float*)d_in[3];
    const float* n1b      = (const float*)d_in[4];
    const float* n2w      = (const float*)d_in[5];
    const float* n2b      = (const float*)d_in[6];
    const float* gcn_w    = (const float*)d_in[7];
    const float* gcn_b    = (const float*)d_in[8];
    const float* conv_w   = (const float*)d_in[9];
    const float* conv_b   = (const float*)d_in[10];
    const float* ggw      = (const float*)d_in[11];
    const float* ggb      = (const float*)d_in[12];
    const float* gmw      = (const float*)d_in[13];
    const float* gmb      = (const float*)d_in[14];
    const float* ow       = (const float*)d_in[15];
    const float* ob       = (const float*)d_in[16];
    const float* m_in_w   = (const float*)d_in[17];
    const float* m_conv_w = (const float*)d_in[18];
    const float* m_conv_b = (const float*)d_in[19];
    const float* m_xproj_w= (const float*)d_in[20];
    const float* m_dt_w   = (const float*)d_in[21];
    const float* m_dt_b   = (const float*)d_in[22];
    const float* m_A_log  = (const float*)d_in[23];
    const float* m_D      = (const float*)d_in[24];
    const float* m_out_w  = (const float*)d_in[25];

    float* out_main = (float*)d_out;
    float* out_adj  = out_main + (size_t)M_ROWS * DM;

    // fp32 workspace, total 30,212,096 floats = 120.8 MB
    float* ws    = (float*)d_ws;
    float* xn    = ws;                    // 3,145,728  (xmamba aliases after death)
    float* xgcn  = xn + 3145728;          // 3,145,728
    float* zbuf  = xgcn + 3145728;        // 6,291,456  (gatebuf/fused + outtmp alias)
    float* xmraw = zbuf + 6291456;        // 6,291,456  (dtb aliases after dwconv)
    float* xmc   = xmraw + 6291456;       // 6,291,456  (scan writes y in place)
    float* xdbl  = xmc + 6291456;         //   327,680
    float* wcat  = xdbl + 327680;         // 4,718,592
    float* xmamba = xn;                   // alias (xn dead after in_proj GEMMs)
    float* dtb    = xmraw;                // alias (xmraw dead after dwconv)
    float* gatebuf = zbuf;                // alias (z dead after scan)
    float* fused   = gatebuf;             // in-place fuse
    float* outtmp  = zbuf + 3145728;      // alias (z second half)

    const dim3 blk(256);

    // adjacency output
    adj_k<<<16, blk, 0, stream>>>(nv1, nv2, out_adj);
    // xn = LN1(x)
    ln_k<<<M_ROWS, blk, 0, stream>>>(x, nullptr, n1w, n1b, xn);
    // concatenated conv+gcn weights
    wcat_k<<<(8 * DM * DM + 255) / 256, blk, 0, stream>>>(conv_w, gcn_w, wcat);
    // x_gcn = xn@gcn_w + gcn_b + dense 'same' conv over L (one fused GEMM, K=6144)
    gemm_k<<<dim3(64, 12), blk, 0, stream>>>(xn, DM, wcat, DM, conv_b, gcn_b,
                                             xgcn, DM, M_ROWS, DM, 8 * DM, 4);
    // xm_raw = xn @ m_in_w[:, :DI] ; z = xn @ m_in_w[:, DI:]
    gemm_k<<<dim3(64, 24), blk, 0, stream>>>(xn, DM, m_in_w, 2 * DI, nullptr, nullptr,
                                             xmraw, DI, M_ROWS, DI, DM, 0);
    gemm_k<<<dim3(64, 24), blk, 0, stream>>>(xn, DM, m_in_w + DI, 2 * DI, nullptr, nullptr,
                                             zbuf, DI, M_ROWS, DI, DM, 0);
    // xm = silu(depthwise_causal_conv(xm_raw) + bias)
    dwconv_silu_k<<<(M_ROWS * DI + 255) / 256, blk, 0, stream>>>(xmraw, m_conv_w, m_conv_b, xmc);
    // x_dbl = xm @ m_xproj_w
    gemm_k<<<dim3(64, 2), blk, 0, stream>>>(xmc, DI, m_xproj_w, 80, nullptr, nullptr,
                                            xdbl, 80, M_ROWS, 80, DI, 0);
    // dt = softplus(x_dbl[:, :48] @ m_dt_w + m_dt_b)   (overwrites xmraw)
    gemm_k<<<dim3(64, 24), blk, 0, stream>>>(xdbl, 80, m_dt_w, DI, m_dt_b, nullptr,
                                             dtb, DI, M_ROWS, DI, DTRANK, 2);
    // selective scan -> y in place over xmc (includes +D*xm and *silu(z))
    scan_k<<<(B_SZ * DI * 16) / 256, blk, 0, stream>>>(dtb, xmc, xdbl, zbuf, m_A_log, m_D);
    // x_mamba = y @ m_out_w   (overwrites xn)
    gemm_k<<<dim3(64, 12), blk, 0, stream>>>(xmc, DI, m_out_w, DM, nullptr, nullptr,
                                             xmamba, DM, M_ROWS, DM, DI, 0);
    // gate pre-activation = xgcn@ggw + ggb + xmamba@gmw + gmb
    gemm_k<<<dim3(64, 12), blk, 0, stream>>>(xgcn, DM, ggw, DM, ggb, nullptr,
                                             gatebuf, DM, M_ROWS, DM, DM, 0);
    gemm_k<<<dim3(64, 12), blk, 0, stream>>>(xmamba, DM, gmw, DM, gmb, nullptr,
                                             gatebuf, DM, M_ROWS, DM, DM, 1);
    // fused = sigmoid(gate)*xgcn + (1-sigmoid)*xmamba  (in place)
    fuse_k<<<(M_ROWS * DM + 255) / 256, blk, 0, stream>>>(gatebuf, xgcn, xmamba, fused);
    // out = fused @ out_w + out_b
    gemm_k<<<dim3(64, 12), blk, 0, stream>>>(fused, DM, ow, DM, ob, nullptr,
                                             outtmp, DM, M_ROWS, DM, DM, 0);
    // final: LN2(outtmp + x) -> fp32 out
    ln_k<<<M_ROWS, blk, 0, stream>>>(outtmp, x, n2w, n2b, out_main);
}

// Round 5
// 1105.248 us; speedup vs baseline: 1.9434x; 1.9434x over previous
//
#include <hip/hip_runtime.h>
#include <math.h>

typedef unsigned short ushort_t;

#define B_SZ 8
#define LSEQ 512
#define DM 768
#define DI 1536
#define DSTATE 16
#define DTRANK 48
#define M_ROWS (B_SZ * LSEQ)   // 4096

#define FLAG_SP   1
#define FLAG_CONV 2

using short8v = __attribute__((ext_vector_type(8))) short;
using float4v = __attribute__((ext_vector_type(4))) float;

__device__ __forceinline__ float us2f(ushort_t u) {
    union { unsigned int i; float f; } cv; cv.i = ((unsigned int)u) << 16; return cv.f;
}
__device__ __forceinline__ ushort_t f2bs(float f) {
    union { float f; unsigned int u; } cv; cv.f = f;
    unsigned int r = cv.u + 0x7FFFu + ((cv.u >> 16) & 1u);   // RNE
    return (ushort_t)(r >> 16);
}

// ---------------------------------------------------------------------------
// MFMA GEMM: C[M=4096][N] = A[4096][lda](bf16) @ Wt^T + b1 + b2
//   Wt is [N][K] bf16 (pre-transposed weights, row length == K)
//   flags: FLAG_SP softplus epilogue; FLAG_CONV: K = 8 segs of 768, seg s<7
//          reads A rows shifted by s-3 within each L=512 slice (seg 7 plain)
// Tile 128x128 x BK=64, 256 thr = 4 waves of 64x64, mfma_f32_16x16x32_bf16.
// LDS chunk-major [k-chunk][row][8] -> all b128, conflict-free.
// ---------------------------------------------------------------------------
__global__ __launch_bounds__(256) void gemm_k(
    const ushort_t* __restrict__ A, int lda,
    const ushort_t* __restrict__ Wt,
    const float* __restrict__ b1, const float* __restrict__ b2,
    float* __restrict__ Cf, ushort_t* __restrict__ Cb, int ldc,
    int N, int K, int flags)
{
    __shared__ short Alds[8][128][8];
    __shared__ short Blds[8][128][8];

    const int tid  = threadIdx.x;
    const int bm   = blockIdx.x * 128;
    const int bn   = blockIdx.y * 128;
    const int wave = tid >> 6;
    const int lane = tid & 63;
    const int l16  = lane & 15;
    const int quad = lane >> 4;
    const int wm   = (wave & 1) * 64;
    const int wn   = (wave >> 1) * 64;

    // staging: row sm (0..127), chunk group grp (0/1 -> chunks 4*grp..4*grp+3)
    const int sm  = tid & 127;
    const int grp = tid >> 7;
    const int mg  = bm + sm;
    const int bidx = mg >> 9;
    const int lrow = mg & 511;
    const int ng  = bn + sm;

    float4v acc[4][4];
    #pragma unroll
    for (int i = 0; i < 4; i++)
        #pragma unroll
        for (int j = 0; j < 4; j++)
            acc[i][j] = (float4v){0.f, 0.f, 0.f, 0.f};

    const int nkt = (K + 63) >> 6;
    for (int kt = 0; kt < nkt; ++kt) {
        const int k0 = kt << 6;
        const ushort_t* arow;
        bool avalid = true;
        if (flags & FLAG_CONV) {
            const int seg  = kt / 12;
            const int koff = (kt - seg * 12) << 6;
            const int sh   = (seg < 7) ? (seg - 3) : 0;
            const int ls   = lrow + sh;
            avalid = (ls >= 0) && (ls < LSEQ);
            arow = A + (size_t)(bidx * LSEQ + (avalid ? ls : 0)) * lda + koff;
        } else {
            arow = A + (size_t)mg * lda + k0;
        }
        const ushort_t* brow = Wt + (size_t)ng * K + k0;
        const bool nvalid = (ng < N);

        #pragma unroll
        for (int i = 0; i < 4; i++) {
            const int c = grp * 4 + i;
            const bool kv = (k0 + c * 8) < K;
            short8v v = {0, 0, 0, 0, 0, 0, 0, 0};
            if (avalid && kv) v = *(const short8v*)(arow + c * 8);
            *(short8v*)(&Alds[c][sm][0]) = v;
            short8v w = {0, 0, 0, 0, 0, 0, 0, 0};
            if (nvalid && kv) w = *(const short8v*)(brow + c * 8);
            *(short8v*)(&Blds[c][sm][0]) = w;
        }
        __syncthreads();

        short8v a0[4], a1[4], b0[4], b1v[4];
        #pragma unroll
        for (int mi = 0; mi < 4; mi++) {
            const int ar = wm + mi * 16 + l16;
            a0[mi] = *(const short8v*)(&Alds[quad][ar][0]);
            a1[mi] = *(const short8v*)(&Alds[4 + quad][ar][0]);
        }
        #pragma unroll
        for (int ni = 0; ni < 4; ni++) {
            const int br = wn + ni * 16 + l16;
            b0[ni] = *(const short8v*)(&Blds[quad][br][0]);
            b1v[ni] = *(const short8v*)(&Blds[4 + quad][br][0]);
        }
        #pragma unroll
        for (int mi = 0; mi < 4; mi++)
            #pragma unroll
            for (int ni = 0; ni < 4; ni++) {
                acc[mi][ni] = __builtin_amdgcn_mfma_f32_16x16x32_bf16(
                    a0[mi], b0[ni], acc[mi][ni], 0, 0, 0);
                acc[mi][ni] = __builtin_amdgcn_mfma_f32_16x16x32_bf16(
                    a1[mi], b1v[ni], acc[mi][ni], 0, 0, 0);
            }
        __syncthreads();
    }

    // epilogue: C col = lane&15, row = quad*4 + reg
    #pragma unroll
    for (int ni = 0; ni < 4; ni++) {
        const int col = bn + wn + ni * 16 + l16;
        if (col >= N) continue;
        const float bias = (b1 ? b1[col] : 0.f) + (b2 ? b2[col] : 0.f);
        #pragma unroll
        for (int mi = 0; mi < 4; mi++) {
            const int row0 = bm + wm + mi * 16 + quad * 4;
            #pragma unroll
            for (int r = 0; r < 4; r++) {
                float v = acc[mi][ni][r] + bias;
                if (flags & FLAG_SP) v = (v > 20.f) ? v : log1pf(__expf(v));
                const size_t idx = (size_t)(row0 + r) * ldc + col;
                if (Cf) Cf[idx] = v;
                else    Cb[idx] = f2bs(v);
            }
        }
    }
}

// adj = sigmoid(nv1 @ nv2) * (1 - eye)  -> fp32
__global__ void adj_k(const float* __restrict__ nv1, const float* __restrict__ nv2,
                      float* __restrict__ out)
{
    int t = blockIdx.x * 256 + threadIdx.x;
    if (t >= 64 * 64) return;
    int i = t >> 6, j = t & 63;
    float s = 0.f;
    #pragma unroll
    for (int k = 0; k < 16; k++) s += nv1[i * 16 + k] * nv2[k * 64 + j];
    out[t] = (i == j) ? 0.f : 1.f / (1.f + __expf(-s));
}

// LayerNorm over last dim (768): LN(xin (+ addf)) * w + b -> fp32 and/or bf16
__global__ __launch_bounds__(256) void ln_k(
    const float* __restrict__ xin, const float* __restrict__ addf,
    const float* __restrict__ w, const float* __restrict__ bparam,
    float* __restrict__ outf, ushort_t* __restrict__ outb)
{
    const int r = blockIdx.x;
    const int tid = threadIdx.x;
    const size_t base = (size_t)r * DM;
    float v[3];
    float s = 0.f, ss = 0.f;
    #pragma unroll
    for (int j = 0; j < 3; j++) {
        const int c = tid + 256 * j;
        float vv = xin[base + c];
        if (addf) vv += addf[base + c];
        v[j] = vv; s += vv; ss += vv * vv;
    }
    #pragma unroll
    for (int o = 32; o > 0; o >>= 1) { s += __shfl_down(s, o); ss += __shfl_down(ss, o); }
    __shared__ float sw[4], ssw[4];
    __shared__ float mu_s, rs_s;
    const int wid = tid >> 6;
    if ((tid & 63) == 0) { sw[wid] = s; ssw[wid] = ss; }
    __syncthreads();
    if (tid == 0) {
        float st = 0.f, sst = 0.f;
        #pragma unroll
        for (int i = 0; i < 4; i++) { st += sw[i]; sst += ssw[i]; }
        const float mu = st / (float)DM;
        const float var = sst / (float)DM - mu * mu;
        mu_s = mu; rs_s = rsqrtf(fmaxf(var, 0.f) + 1e-5f);
    }
    __syncthreads();
    const float mu = mu_s, rs = rs_s;
    #pragma unroll
    for (int j = 0; j < 3; j++) {
        const int c = tid + 256 * j;
        const float o = (v[j] - mu) * rs * w[c] + bparam[c];
        if (outf) outf[base + c] = o;
        if (outb) outb[base + c] = f2bs(o);
    }
}

// tiled transpose + cvt: in fp32 [R][C] -> out bf16 [C-major]: out[c*ldout+off+r]
__global__ void tcvt_k(const float* __restrict__ in, int R, int C,
                       ushort_t* __restrict__ out, int ldout, int off)
{
    __shared__ float tile[32][33];
    const int c0 = blockIdx.x * 32, r0 = blockIdx.y * 32;
    const int tx = threadIdx.x, ty = threadIdx.y;   // (32, 8)
    #pragma unroll
    for (int j = 0; j < 4; j++) {
        const int rr = r0 + ty + j * 8;
        if (rr < R && c0 + tx < C) tile[ty + j * 8][tx] = in[(size_t)rr * C + c0 + tx];
    }
    __syncthreads();
    #pragma unroll
    for (int j = 0; j < 4; j++) {
        const int cc = c0 + ty + j * 8;
        const int kk = r0 + tx;
        if (cc < C && kk < R)
            out[(size_t)cc * ldout + off + kk] = f2bs(tile[tx][ty + j * 8]);
    }
}

// wcat_t[768][6144]: [o][seg*768+i] = conv_w[o,i,seg] (seg<7); seg7 = gcn_w[i][o]
__global__ void wcat_k(const float* __restrict__ cw, const float* __restrict__ gw,
                       ushort_t* __restrict__ out)
{
    int t = blockIdx.x * 256 + threadIdx.x;
    if (t >= DM * 8 * DM) return;
    const int o = t / (8 * DM);
    const int rr = t - o * 8 * DM;
    const int seg = rr / DM;
    const int i = rr - seg * DM;
    float v = (seg < 7) ? cw[(size_t)o * (DM * 7) + i * 7 + seg]
                        : gw[(size_t)i * DM + o];
    out[t] = f2bs(v);
}

// depthwise causal conv (D_CONV=4) + bias + silu; xz bf16 [4096][3072] (xm half)
__global__ void dwconv_k(const ushort_t* __restrict__ xz, const float* __restrict__ w,
                         const float* __restrict__ bcv, ushort_t* __restrict__ out)
{
    int t = blockIdx.x * 256 + threadIdx.x;
    if (t >= M_ROWS * DI) return;
    const int d = t % DI;
    const int bl = t / DI;
    const int l = bl & 511;
    const ushort_t* xp = xz + (size_t)bl * (2 * DI) + d;
    float s = bcv[d];
    #pragma unroll
    for (int k = 0; k < 4; k++) {
        const int ls = l + k - 3;
        if (ls >= 0) s += w[d * 4 + k] * us2f(xp[(ptrdiff_t)(k - 3) * (2 * DI)]);
    }
    out[t] = f2bs(s / (1.f + __expf(-s)));
}

// selective scan: 16 lanes per (b,d); dt fp32, xm/B/C/z bf16; y bf16 in place
__global__ __launch_bounds__(256) void scan_k(
    const float* __restrict__ dtb, ushort_t* __restrict__ xmc,
    const ushort_t* __restrict__ xdbl, const ushort_t* __restrict__ xz,
    const float* __restrict__ A_log, const float* __restrict__ Dp)
{
    const int t = blockIdx.x * 256 + threadIdx.x;
    const int lane = t & 15;
    const int g = t >> 4;
    if (g >= B_SZ * DI) return;
    const int d = g % DI;
    const int b = g / DI;
    const float Ad = -__expf(A_log[d * DSTATE + lane]);
    const float Dd = Dp[d];
    float h = 0.f;
    const float* dtp   = dtb + (size_t)b * LSEQ * DI + d;
    ushort_t*    xp    = xmc + (size_t)b * LSEQ * DI + d;
    const ushort_t* bp = xdbl + (size_t)b * LSEQ * 80 + DTRANK + lane;
    const ushort_t* cp = bp + DSTATE;
    const ushort_t* zp = xz + (size_t)b * LSEQ * (2 * DI) + DI + d;
    for (int l = 0; l < LSEQ; ++l) {
        const float dtv = dtp[(size_t)l * DI];
        const float xv  = us2f(xp[(size_t)l * DI]);
        const float Bv  = us2f(bp[(size_t)l * 80]);
        const float Cv  = us2f(cp[(size_t)l * 80]);
        h = __expf(dtv * Ad) * h + dtv * Bv * xv;
        float p = h * Cv;
        p += __shfl_xor(p, 1);
        p += __shfl_xor(p, 2);
        p += __shfl_xor(p, 4);
        p += __shfl_xor(p, 8);
        if (lane == 0) {
            const float zv = us2f(zp[(size_t)l * (2 * DI)]);
            const float sz = zv / (1.f + __expf(-zv));
            xp[(size_t)l * DI] = f2bs((p + Dd * xv) * sz);
        }
    }
}

// fused = sigmoid(gate)*xgcn + (1-sig)*xmamba ; gcnmam = [xgcn | xmamba] bf16
__global__ void fuse_k(const ushort_t* __restrict__ gb, const ushort_t* __restrict__ gm,
                       ushort_t* __restrict__ fused)
{
    int t = blockIdx.x * 256 + threadIdx.x;
    if (t >= M_ROWS * DM) return;
    const int bl = t / DM, c = t - bl * DM;
    const float g = 1.f / (1.f + __expf(-us2f(gb[t])));
    const float xg = us2f(gm[(size_t)bl * (2 * DM) + c]);
    const float xm = us2f(gm[(size_t)bl * (2 * DM) + DM + c]);
    fused[t] = f2bs(g * xg + (1.f - g) * xm);
}

extern "C" void kernel_launch(void* const* d_in, const int* in_sizes, int n_in,
                              void* d_out, int out_size, void* d_ws, size_t ws_size,
                              hipStream_t stream)
{
    const float* x        = (const float*)d_in[0];
    const float* nv1      = (const float*)d_in[1];
    const float* nv2      = (const float*)d_in[2];
    const float* n1w      = (const float*)d_in[3];
    const float* n1b      = (const float*)d_in[4];
    const float* n2w      = (const float*)d_in[5];
    const float* n2b      = (const float*)d_in[6];
    const float* gcn_w    = (const float*)d_in[7];
    const float* gcn_b    = (const float*)d_in[8];
    const float* conv_w   = (const float*)d_in[9];
    const float* conv_b   = (const float*)d_in[10];
    const float* ggw      = (const float*)d_in[11];
    const float* ggb      = (const float*)d_in[12];
    const float* gmw      = (const float*)d_in[13];
    const float* gmb      = (const float*)d_in[14];
    const float* ow       = (const float*)d_in[15];
    const float* ob       = (const float*)d_in[16];
    const float* m_in_w   = (const float*)d_in[17];
    const float* m_conv_w = (const float*)d_in[18];
    const float* m_conv_b = (const float*)d_in[19];
    const float* m_xproj_w= (const float*)d_in[20];
    const float* m_dt_w   = (const float*)d_in[21];
    const float* m_dt_b   = (const float*)d_in[22];
    const float* m_A_log  = (const float*)d_in[23];
    const float* m_D      = (const float*)d_in[24];
    const float* m_out_w  = (const float*)d_in[25];

    float* out_main = (float*)d_out;
    float* out_adj  = out_main + (size_t)M_ROWS * DM;

    // workspace: bf16 region then fp32 region; total ~102.9 MB
    ushort_t* wsb = (ushort_t*)d_ws;
    ushort_t* xn_bf   = wsb;                       //  3,145,728
    ushort_t* xz_bf   = xn_bf   + 3145728;         // 12,582,912
    ushort_t* xmc_bf  = xz_bf   + 12582912;        //  6,291,456 (y in place)
    ushort_t* xdbl_bf = xmc_bf  + 6291456;         //    327,680
    ushort_t* gcnmam  = xdbl_bf + 327680;          //  6,291,456 [xgcn|xmamba]
    ushort_t* wcat_t  = gcnmam  + 6291456;         //  4,718,592
    ushort_t* in_w_t  = wcat_t  + 4718592;         //  2,359,296
    ushort_t* xproj_t = in_w_t  + 2359296;         //    122,880
    ushort_t* dtw_t   = xproj_t + 122880;          //     73,728
    ushort_t* outw_t  = dtw_t   + 73728;           //  1,179,648
    ushort_t* gates_t = outw_t  + 1179648;         //  1,179,648
    ushort_t* ow_t    = gates_t + 1179648;         //    589,824
    float*    dtb     = (float*)(ow_t + 589824);   //  6,291,456 fp32
    // aliases
    ushort_t* gatebuf = xz_bf;                     // (xz dead after scan)
    ushort_t* fused   = xz_bf + 3145728;
    float*    outtmp  = dtb;                       // (dtb dead after scan)

    const dim3 blk(256);
    const dim3 tblk(32, 8);

    // ---- weight prep (bf16, transposed) ----
    wcat_k<<<(DM * 8 * DM + 255) / 256, blk, 0, stream>>>(conv_w, gcn_w, wcat_t);
    tcvt_k<<<dim3(3072 / 32, 768 / 32), tblk, 0, stream>>>(m_in_w, 768, 3072, in_w_t, 768, 0);
    tcvt_k<<<dim3(3, 1536 / 32), tblk, 0, stream>>>(m_xproj_w, 1536, 80, xproj_t, 1536, 0);
    tcvt_k<<<dim3(1536 / 32, 2), tblk, 0, stream>>>(m_dt_w, 48, 1536, dtw_t, 48, 0);
    tcvt_k<<<dim3(768 / 32, 1536 / 32), tblk, 0, stream>>>(m_out_w, 1536, 768, outw_t, 1536, 0);
    tcvt_k<<<dim3(768 / 32, 768 / 32), tblk, 0, stream>>>(ggw, 768, 768, gates_t, 1536, 0);
    tcvt_k<<<dim3(768 / 32, 768 / 32), tblk, 0, stream>>>(gmw, 768, 768, gates_t, 1536, 768);
    tcvt_k<<<dim3(768 / 32, 768 / 32), tblk, 0, stream>>>(ow, 768, 768, ow_t, 768, 0);

    // ---- forward ----
    adj_k<<<16, blk, 0, stream>>>(nv1, nv2, out_adj);
    ln_k<<<M_ROWS, blk, 0, stream>>>(x, nullptr, n1w, n1b, nullptr, xn_bf);

    // x_gcn (+ conv over L): -> gcnmam[:, 0:768] bf16
    gemm_k<<<dim3(32, 6), blk, 0, stream>>>(xn_bf, DM, wcat_t, conv_b, gcn_b,
                                            nullptr, gcnmam, 2 * DM, DM, 8 * DM, FLAG_CONV);
    // xz = xn @ m_in_w -> bf16 [4096][3072]
    gemm_k<<<dim3(32, 24), blk, 0, stream>>>(xn_bf, DM, in_w_t, nullptr, nullptr,
                                             nullptr, xz_bf, 2 * DI, 2 * DI, DM, 0);
    // xm = silu(dwconv(xm)) -> xmc bf16
    dwconv_k<<<(M_ROWS * DI + 255) / 256, blk, 0, stream>>>(xz_bf, m_conv_w, m_conv_b, xmc_bf);
    // x_dbl = xm @ m_xproj_w -> bf16 [4096][80]
    gemm_k<<<dim3(32, 1), blk, 0, stream>>>(xmc_bf, DI, xproj_t, nullptr, nullptr,
                                            nullptr, xdbl_bf, 80, 80, DI, 0);
    // dt = softplus(x_dbl[:, :48] @ m_dt_w + b) -> fp32
    gemm_k<<<dim3(32, 12), blk, 0, stream>>>(xdbl_bf, 80, dtw_t, m_dt_b, nullptr,
                                             dtb, nullptr, DI, DI, DTRANK, FLAG_SP);
    // selective scan -> y bf16 in place over xmc
    scan_k<<<(B_SZ * DI * 16) / 256, blk, 0, stream>>>(dtb, xmc_bf, xdbl_bf, xz_bf, m_A_log, m_D);
    // x_mamba = y @ m_out_w -> gcnmam[:, 768:1536] bf16
    gemm_k<<<dim3(32, 6), blk, 0, stream>>>(xmc_bf, DI, outw_t, nullptr, nullptr,
                                            nullptr, gcnmam + DM, 2 * DM, DM, DI, 0);
    // gate = [xgcn|xmamba] @ [ggw;gmw] + ggb + gmb -> bf16 (over dead xz)
    gemm_k<<<dim3(32, 6), blk, 0, stream>>>(gcnmam, 2 * DM, gates_t, ggb, gmb,
                                            nullptr, gatebuf, DM, DM, 2 * DM, 0);
    // fused = sig(gate)*xgcn + (1-sig)*xmamba -> bf16
    fuse_k<<<(M_ROWS * DM + 255) / 256, blk, 0, stream>>>(gatebuf, gcnmam, fused);
    // out = fused @ out_w + ob -> fp32 (over dead dtb)
    gemm_k<<<dim3(32, 6), blk, 0, stream>>>(fused, DM, ow_t, ob, nullptr,
                                            outtmp, nullptr, DM, DM, DM, 0);
    // final LN2(outtmp + x) -> fp32 d_out
    ln_k<<<M_ROWS, blk, 0, stream>>>(outtmp, x, n2w, n2b, out_main, nullptr);
}

// Round 6
// 866.250 us; speedup vs baseline: 2.4796x; 1.2759x over previous
//
#include <hip/hip_runtime.h>
#include <math.h>

typedef unsigned short ushort_t;

#define B_SZ 8
#define LSEQ 512
#define DM 768
#define DI 1536
#define DSTATE 16
#define DTRANK 48
#define M_ROWS (B_SZ * LSEQ)   // 4096

#define FLAG_SP   1
#define FLAG_CONV 2

using short8v = __attribute__((ext_vector_type(8))) short;
using float4v = __attribute__((ext_vector_type(4))) float;

__device__ __forceinline__ float us2f(ushort_t u) {
    union { unsigned int i; float f; } cv; cv.i = ((unsigned int)u) << 16; return cv.f;
}
__device__ __forceinline__ ushort_t f2bs(float f) {
    union { float f; unsigned int u; } cv; cv.f = f;
    unsigned int r = cv.u + 0x7FFFu + ((cv.u >> 16) & 1u);   // RNE
    return (ushort_t)(r >> 16);
}

// ---------------------------------------------------------------------------
// MFMA GEMM: C[M=4096][N] = A[4096][lda](bf16) @ Wt^T + b1 + b2
//   Wt is [N][K] bf16 (pre-transposed weights, row length == K)
//   flags: FLAG_SP softplus; FLAG_CONV: K = 8 segs of 768, seg s<7 reads A
//          rows shifted by s-3 within each L=512 slice (seg 7 plain)
// Tile 128 x TN x BK=64, 256 thr = 4 waves (2x2 of 64 x TN/2).
// ---------------------------------------------------------------------------
template <int TN>
__global__ __launch_bounds__(256) void gemm_k(
    const ushort_t* __restrict__ A, int lda,
    const ushort_t* __restrict__ Wt,
    const float* __restrict__ b1, const float* __restrict__ b2,
    float* __restrict__ Cf, ushort_t* __restrict__ Cb, int ldc,
    int N, int K, int flags)
{
    constexpr int NF = TN / 32;          // n-fragments per wave
    __shared__ short Alds[8][128][8];
    __shared__ short Blds[8][TN][8];

    const int tid  = threadIdx.x;
    const int bm   = blockIdx.x * 128;
    const int bn   = blockIdx.y * TN;
    const int wave = tid >> 6;
    const int lane = tid & 63;
    const int l16  = lane & 15;
    const int quad = lane >> 4;
    const int wm   = (wave & 1) * 64;
    const int wn   = (wave >> 1) * (TN / 2);

    const int sm  = tid & 127;
    const int grp = tid >> 7;
    const int mg  = bm + sm;
    const int bidx = mg >> 9;
    const int lrow = mg & 511;
    const int ng  = bn + sm;

    float4v acc[4][NF];
    #pragma unroll
    for (int i = 0; i < 4; i++)
        #pragma unroll
        for (int j = 0; j < NF; j++)
            acc[i][j] = (float4v){0.f, 0.f, 0.f, 0.f};

    const int nkt = (K + 63) >> 6;
    for (int kt = 0; kt < nkt; ++kt) {
        const int k0 = kt << 6;
        const ushort_t* arow;
        bool avalid = true;
        if (flags & FLAG_CONV) {
            const int seg  = kt / 12;
            const int koff = (kt - seg * 12) << 6;
            const int sh   = (seg < 7) ? (seg - 3) : 0;
            const int ls   = lrow + sh;
            avalid = (ls >= 0) && (ls < LSEQ);
            arow = A + (size_t)(bidx * LSEQ + (avalid ? ls : 0)) * lda + koff;
        } else {
            arow = A + (size_t)mg * lda + k0;
        }
        const ushort_t* brow = Wt + (size_t)ng * K + k0;
        const bool nvalid = (sm < TN) && (ng < N);

        #pragma unroll
        for (int i = 0; i < 4; i++) {
            const int c = grp * 4 + i;
            const bool kv = (k0 + c * 8) < K;
            short8v v = {0, 0, 0, 0, 0, 0, 0, 0};
            if (avalid && kv) v = *(const short8v*)(arow + c * 8);
            *(short8v*)(&Alds[c][sm][0]) = v;
            if (sm < TN) {
                short8v w = {0, 0, 0, 0, 0, 0, 0, 0};
                if (nvalid && kv) w = *(const short8v*)(brow + c * 8);
                *(short8v*)(&Blds[c][sm][0]) = w;
            }
        }
        __syncthreads();

        short8v a0[4], a1[4], b0[NF], b1v[NF];
        #pragma unroll
        for (int mi = 0; mi < 4; mi++) {
            const int ar = wm + mi * 16 + l16;
            a0[mi] = *(const short8v*)(&Alds[quad][ar][0]);
            a1[mi] = *(const short8v*)(&Alds[4 + quad][ar][0]);
        }
        #pragma unroll
        for (int ni = 0; ni < NF; ni++) {
            const int br = wn + ni * 16 + l16;
            b0[ni] = *(const short8v*)(&Blds[quad][br][0]);
            b1v[ni] = *(const short8v*)(&Blds[4 + quad][br][0]);
        }
        #pragma unroll
        for (int mi = 0; mi < 4; mi++)
            #pragma unroll
            for (int ni = 0; ni < NF; ni++) {
                acc[mi][ni] = __builtin_amdgcn_mfma_f32_16x16x32_bf16(
                    a0[mi], b0[ni], acc[mi][ni], 0, 0, 0);
                acc[mi][ni] = __builtin_amdgcn_mfma_f32_16x16x32_bf16(
                    a1[mi], b1v[ni], acc[mi][ni], 0, 0, 0);
            }
        __syncthreads();
    }

    #pragma unroll
    for (int ni = 0; ni < NF; ni++) {
        const int col = bn + wn + ni * 16 + l16;
        if (col >= N) continue;
        const float bias = (b1 ? b1[col] : 0.f) + (b2 ? b2[col] : 0.f);
        #pragma unroll
        for (int mi = 0; mi < 4; mi++) {
            const int row0 = bm + wm + mi * 16 + quad * 4;
            #pragma unroll
            for (int r = 0; r < 4; r++) {
                float v = acc[mi][ni][r] + bias;
                if (flags & FLAG_SP) v = (v > 20.f) ? v : log1pf(__expf(v));
                const size_t idx = (size_t)(row0 + r) * ldc + col;
                if (Cf) Cf[idx] = v;
                else    Cb[idx] = f2bs(v);
            }
        }
    }
}

// adj = sigmoid(nv1 @ nv2) * (1 - eye)  -> fp32
__global__ void adj_k(const float* __restrict__ nv1, const float* __restrict__ nv2,
                      float* __restrict__ out)
{
    int t = blockIdx.x * 256 + threadIdx.x;
    if (t >= 64 * 64) return;
    int i = t >> 6, j = t & 63;
    float s = 0.f;
    #pragma unroll
    for (int k = 0; k < 16; k++) s += nv1[i * 16 + k] * nv2[k * 64 + j];
    out[t] = (i == j) ? 0.f : 1.f / (1.f + __expf(-s));
}

// LayerNorm over last dim (768): LN(xin (+ addf)) * w + b -> fp32 and/or bf16
__global__ __launch_bounds__(256) void ln_k(
    const float* __restrict__ xin, const float* __restrict__ addf,
    const float* __restrict__ w, const float* __restrict__ bparam,
    float* __restrict__ outf, ushort_t* __restrict__ outb)
{
    const int r = blockIdx.x;
    const int tid = threadIdx.x;
    const size_t base = (size_t)r * DM;
    float v[3];
    float s = 0.f, ss = 0.f;
    #pragma unroll
    for (int j = 0; j < 3; j++) {
        const int c = tid + 256 * j;
        float vv = xin[base + c];
        if (addf) vv += addf[base + c];
        v[j] = vv; s += vv; ss += vv * vv;
    }
    #pragma unroll
    for (int o = 32; o > 0; o >>= 1) { s += __shfl_down(s, o); ss += __shfl_down(ss, o); }
    __shared__ float sw[4], ssw[4];
    __shared__ float mu_s, rs_s;
    const int wid = tid >> 6;
    if ((tid & 63) == 0) { sw[wid] = s; ssw[wid] = ss; }
    __syncthreads();
    if (tid == 0) {
        float st = 0.f, sst = 0.f;
        #pragma unroll
        for (int i = 0; i < 4; i++) { st += sw[i]; sst += ssw[i]; }
        const float mu = st / (float)DM;
        const float var = sst / (float)DM - mu * mu;
        mu_s = mu; rs_s = rsqrtf(fmaxf(var, 0.f) + 1e-5f);
    }
    __syncthreads();
    const float mu = mu_s, rs = rs_s;
    #pragma unroll
    for (int j = 0; j < 3; j++) {
        const int c = tid + 256 * j;
        const float o = (v[j] - mu) * rs * w[c] + bparam[c];
        if (outf) outf[base + c] = o;
        if (outb) outb[base + c] = f2bs(o);
    }
}

// tiled transpose + cvt: in fp32 [R][C] -> out bf16 [C-major]: out[c*ldout+off+r]
__global__ void tcvt_k(const float* __restrict__ in, int R, int C,
                       ushort_t* __restrict__ out, int ldout, int off)
{
    __shared__ float tile[32][33];
    const int c0 = blockIdx.x * 32, r0 = blockIdx.y * 32;
    const int tx = threadIdx.x, ty = threadIdx.y;   // (32, 8)
    #pragma unroll
    for (int j = 0; j < 4; j++) {
        const int rr = r0 + ty + j * 8;
        if (rr < R && c0 + tx < C) tile[ty + j * 8][tx] = in[(size_t)rr * C + c0 + tx];
    }
    __syncthreads();
    #pragma unroll
    for (int j = 0; j < 4; j++) {
        const int cc = c0 + ty + j * 8;
        const int kk = r0 + tx;
        if (cc < C && kk < R)
            out[(size_t)cc * ldout + off + kk] = f2bs(tile[tx][ty + j * 8]);
    }
}

// wcat_t[768][6144]: [o][seg*768+i] = conv_w[o,i,seg] (seg<7); seg7 = gcn_w[i][o]
__global__ void wcat_k(const float* __restrict__ cw, const float* __restrict__ gw,
                       ushort_t* __restrict__ out)
{
    int t = blockIdx.x * 256 + threadIdx.x;
    if (t >= DM * 8 * DM) return;
    const int o = t / (8 * DM);
    const int rr = t - o * 8 * DM;
    const int seg = rr / DM;
    const int i = rr - seg * DM;
    float v = (seg < 7) ? cw[(size_t)o * (DM * 7) + i * 7 + seg]
                        : gw[(size_t)i * DM + o];
    out[t] = f2bs(v);
}

// depthwise causal conv (D_CONV=4) + bias + silu; xz bf16 [4096][3072] (xm half)
__global__ void dwconv_k(const ushort_t* __restrict__ xz, const float* __restrict__ w,
                         const float* __restrict__ bcv, ushort_t* __restrict__ out)
{
    int t = blockIdx.x * 256 + threadIdx.x;
    if (t >= M_ROWS * DI) return;
    const int d = t % DI;
    const int bl = t / DI;
    const int l = bl & 511;
    const ushort_t* xp = xz + (size_t)bl * (2 * DI) + d;
    float s = bcv[d];
    #pragma unroll
    for (int k = 0; k < 4; k++) {
        const int ls = l + k - 3;
        if (ls >= 0) s += w[d * 4 + k] * us2f(xp[(ptrdiff_t)(k - 3) * (2 * DI)]);
    }
    out[t] = f2bs(s / (1.f + __expf(-s)));
}

// ---------------------------------------------------------------------------
// Tiled selective scan. Block 256 = 16 d x 16 n; grid (DI/16, B).
// L processed in tiles of 32, staged reg->LDS (coalesced); y staged via LDS.
// ---------------------------------------------------------------------------
#define SDT 16
#define STL 32
__global__ __launch_bounds__(256) void scan_k(
    const float* __restrict__ dtb, ushort_t* __restrict__ xmc,
    const ushort_t* __restrict__ xdbl, const ushort_t* __restrict__ xz,
    const float* __restrict__ A_log, const float* __restrict__ Dp)
{
    __shared__ float    dt_s[STL][SDT];
    __shared__ ushort_t xm_s[STL][SDT];
    __shared__ ushort_t z_s [STL][SDT];
    __shared__ ushort_t Bv_s[STL][16];
    __shared__ ushort_t Cv_s[STL][16];
    __shared__ ushort_t y_s [STL][SDT];

    const int tid = threadIdx.x;
    const int dl  = tid >> 4;
    const int n   = tid & 15;
    const int b   = blockIdx.y;
    const int d0  = blockIdx.x * SDT;
    const int d   = d0 + dl;

    const float Ad = -__expf(A_log[d * DSTATE + n]);
    const float Dd = Dp[d];

    const float*    dtp = dtb + (size_t)b * LSEQ * DI;
    ushort_t*       xmp = xmc + (size_t)b * LSEQ * DI;
    const ushort_t* zp  = xz  + (size_t)b * LSEQ * (2 * DI) + DI;
    const ushort_t* dbp = xdbl + (size_t)b * LSEQ * 80;

    float    dt_r[2];
    ushort_t xm_r[2], z_r[2], b_r[2], c_r[2];

    auto tload = [&](int l0) {
        #pragma unroll
        for (int e = 0; e < 2; e++) {
            const int idx = tid + e * 256;
            const int ll = idx >> 4, dc = idx & 15;
            const size_t ro = (size_t)(l0 + ll);
            dt_r[e] = dtp[ro * DI + d0 + dc];
            xm_r[e] = xmp[ro * DI + d0 + dc];
            z_r[e]  = zp [ro * 2 * DI + d0 + dc];
            b_r[e]  = dbp[ro * 80 + DTRANK + dc];
            c_r[e]  = dbp[ro * 80 + DTRANK + DSTATE + dc];
        }
    };

    float h = 0.f;
    tload(0);
    for (int t = 0; t < LSEQ / STL; ++t) {
        __syncthreads();                 // prior tile fully consumed
        #pragma unroll
        for (int e = 0; e < 2; e++) {
            const int idx = tid + e * 256;
            const int ll = idx >> 4, dc = idx & 15;
            dt_s[ll][dc] = dt_r[e];
            xm_s[ll][dc] = xm_r[e];
            z_s [ll][dc] = z_r[e];
            Bv_s[ll][dc] = b_r[e];
            Cv_s[ll][dc] = c_r[e];
        }
        __syncthreads();
        if (t + 1 < LSEQ / STL) tload((t + 1) * STL);   // overlap with compute

        #pragma unroll
        for (int ll = 0; ll < STL; ++ll) {
            const float dtv = dt_s[ll][dl];
            const float xv  = us2f(xm_s[ll][dl]);
            const float Bv  = us2f(Bv_s[ll][n]);
            const float Cv  = us2f(Cv_s[ll][n]);
            h = __expf(dtv * Ad) * h + (dtv * Bv) * xv;
            float p = h * Cv;
            p += __shfl_xor(p, 1);
            p += __shfl_xor(p, 2);
            p += __shfl_xor(p, 4);
            p += __shfl_xor(p, 8);
            if (n == 0) {
                const float zv = us2f(z_s[ll][dl]);
                const float sz = zv / (1.f + __expf(-zv));
                y_s[ll][dl] = f2bs((p + Dd * xv) * sz);
            }
        }
        __syncthreads();                 // y_s ready
        #pragma unroll
        for (int e = 0; e < 2; e++) {
            const int idx = tid + e * 256;
            const int ll = idx >> 4, dc = idx & 15;
            xmp[(size_t)(t * STL + ll) * DI + d0 + dc] = y_s[ll][dc];
        }
    }
}

// fused = sigmoid(gate)*xgcn + (1-sig)*xmamba ; gcnmam = [xgcn | xmamba] bf16
__global__ void fuse_k(const ushort_t* __restrict__ gb, const ushort_t* __restrict__ gm,
                       ushort_t* __restrict__ fused)
{
    int t = blockIdx.x * 256 + threadIdx.x;
    if (t >= M_ROWS * DM) return;
    const int bl = t / DM, c = t - bl * DM;
    const float g = 1.f / (1.f + __expf(-us2f(gb[t])));
    const float xg = us2f(gm[(size_t)bl * (2 * DM) + c]);
    const float xm = us2f(gm[(size_t)bl * (2 * DM) + DM + c]);
    fused[t] = f2bs(g * xg + (1.f - g) * xm);
}

extern "C" void kernel_launch(void* const* d_in, const int* in_sizes, int n_in,
                              void* d_out, int out_size, void* d_ws, size_t ws_size,
                              hipStream_t stream)
{
    const float* x        = (const float*)d_in[0];
    const float* nv1      = (const float*)d_in[1];
    const float* nv2      = (const float*)d_in[2];
    const float* n1w      = (const float*)d_in[3];
    const float* n1b      = (const float*)d_in[4];
    const float* n2w      = (const float*)d_in[5];
    const float* n2b      = (const float*)d_in[6];
    const float* gcn_w    = (const float*)d_in[7];
    const float* gcn_b    = (const float*)d_in[8];
    const float* conv_w   = (const float*)d_in[9];
    const float* conv_b   = (const float*)d_in[10];
    const float* ggw      = (const float*)d_in[11];
    const float* ggb      = (const float*)d_in[12];
    const float* gmw      = (const float*)d_in[13];
    const float* gmb      = (const float*)d_in[14];
    const float* ow       = (const float*)d_in[15];
    const float* ob       = (const float*)d_in[16];
    const float* m_in_w   = (const float*)d_in[17];
    const float* m_conv_w = (const float*)d_in[18];
    const float* m_conv_b = (const float*)d_in[19];
    const float* m_xproj_w= (const float*)d_in[20];
    const float* m_dt_w   = (const float*)d_in[21];
    const float* m_dt_b   = (const float*)d_in[22];
    const float* m_A_log  = (const float*)d_in[23];
    const float* m_D      = (const float*)d_in[24];
    const float* m_out_w  = (const float*)d_in[25];

    float* out_main = (float*)d_out;
    float* out_adj  = out_main + (size_t)M_ROWS * DM;

    // workspace: bf16 region then fp32 region; total ~102.9 MB
    ushort_t* wsb = (ushort_t*)d_ws;
    ushort_t* xn_bf   = wsb;                       //  3,145,728
    ushort_t* xz_bf   = xn_bf   + 3145728;         // 12,582,912
    ushort_t* xmc_bf  = xz_bf   + 12582912;        //  6,291,456 (y in place)
    ushort_t* xdbl_bf = xmc_bf  + 6291456;         //    327,680
    ushort_t* gcnmam  = xdbl_bf + 327680;          //  6,291,456 [xgcn|xmamba]
    ushort_t* wcat_t  = gcnmam  + 6291456;         //  4,718,592
    ushort_t* in_w_t  = wcat_t  + 4718592;         //  2,359,296
    ushort_t* xproj_t = in_w_t  + 2359296;         //    122,880
    ushort_t* dtw_t   = xproj_t + 122880;          //     73,728
    ushort_t* outw_t  = dtw_t   + 73728;           //  1,179,648
    ushort_t* gates_t = outw_t  + 1179648;         //  1,179,648
    ushort_t* ow_t    = gates_t + 1179648;         //    589,824
    float*    dtb     = (float*)(ow_t + 589824);   //  6,291,456 fp32
    // aliases
    ushort_t* gatebuf = xz_bf;                     // (xz dead after scan)
    ushort_t* fused   = xz_bf + 3145728;
    float*    outtmp  = dtb;                       // (dtb dead after scan)

    const dim3 blk(256);
    const dim3 tblk(32, 8);

    // ---- weight prep (bf16, transposed) ----
    wcat_k<<<(DM * 8 * DM + 255) / 256, blk, 0, stream>>>(conv_w, gcn_w, wcat_t);
    tcvt_k<<<dim3(3072 / 32, 768 / 32), tblk, 0, stream>>>(m_in_w, 768, 3072, in_w_t, 768, 0);
    tcvt_k<<<dim3(3, 1536 / 32), tblk, 0, stream>>>(m_xproj_w, 1536, 80, xproj_t, 1536, 0);
    tcvt_k<<<dim3(1536 / 32, 2), tblk, 0, stream>>>(m_dt_w, 48, 1536, dtw_t, 48, 0);
    tcvt_k<<<dim3(768 / 32, 1536 / 32), tblk, 0, stream>>>(m_out_w, 1536, 768, outw_t, 1536, 0);
    tcvt_k<<<dim3(768 / 32, 768 / 32), tblk, 0, stream>>>(ggw, 768, 768, gates_t, 1536, 0);
    tcvt_k<<<dim3(768 / 32, 768 / 32), tblk, 0, stream>>>(gmw, 768, 768, gates_t, 1536, 768);
    tcvt_k<<<dim3(768 / 32, 768 / 32), tblk, 0, stream>>>(ow, 768, 768, ow_t, 768, 0);

    // ---- forward ----
    adj_k<<<16, blk, 0, stream>>>(nv1, nv2, out_adj);
    ln_k<<<M_ROWS, blk, 0, stream>>>(x, nullptr, n1w, n1b, nullptr, xn_bf);

    // x_gcn (+ conv over L): -> gcnmam[:, 0:768] bf16
    gemm_k<64><<<dim3(32, 12), blk, 0, stream>>>(xn_bf, DM, wcat_t, conv_b, gcn_b,
                                                 nullptr, gcnmam, 2 * DM, DM, 8 * DM, FLAG_CONV);
    // xz = xn @ m_in_w -> bf16 [4096][3072]
    gemm_k<128><<<dim3(32, 24), blk, 0, stream>>>(xn_bf, DM, in_w_t, nullptr, nullptr,
                                                  nullptr, xz_bf, 2 * DI, 2 * DI, DM, 0);
    // xm = silu(dwconv(xm)) -> xmc bf16
    dwconv_k<<<(M_ROWS * DI + 255) / 256, blk, 0, stream>>>(xz_bf, m_conv_w, m_conv_b, xmc_bf);
    // x_dbl = xm @ m_xproj_w -> bf16 [4096][80]
    gemm_k<128><<<dim3(32, 1), blk, 0, stream>>>(xmc_bf, DI, xproj_t, nullptr, nullptr,
                                                 nullptr, xdbl_bf, 80, 80, DI, 0);
    // dt = softplus(x_dbl[:, :48] @ m_dt_w + b) -> fp32
    gemm_k<128><<<dim3(32, 12), blk, 0, stream>>>(xdbl_bf, 80, dtw_t, m_dt_b, nullptr,
                                                  dtb, nullptr, DI, DI, DTRANK, FLAG_SP);
    // selective scan -> y bf16 in place over xmc (tiled, LDS-staged)
    scan_k<<<dim3(DI / SDT, B_SZ), blk, 0, stream>>>(dtb, xmc_bf, xdbl_bf, xz_bf, m_A_log, m_D);
    // x_mamba = y @ m_out_w -> gcnmam[:, 768:1536] bf16
    gemm_k<64><<<dim3(32, 12), blk, 0, stream>>>(xmc_bf, DI, outw_t, nullptr, nullptr,
                                                 nullptr, gcnmam + DM, 2 * DM, DM, DI, 0);
    // gate = [xgcn|xmamba] @ [ggw;gmw] + ggb + gmb -> bf16 (over dead xz)
    gemm_k<64><<<dim3(32, 12), blk, 0, stream>>>(gcnmam, 2 * DM, gates_t, ggb, gmb,
                                                 nullptr, gatebuf, DM, DM, 2 * DM, 0);
    // fused = sig(gate)*xgcn + (1-sig)*xmamba -> bf16
    fuse_k<<<(M_ROWS * DM + 255) / 256, blk, 0, stream>>>(gatebuf, gcnmam, fused);
    // out = fused @ out_w + ob -> fp32 (over dead dtb)
    gemm_k<64><<<dim3(32, 12), blk, 0, stream>>>(fused, DM, ow_t, ob, nullptr,
                                                 outtmp, nullptr, DM, DM, DM, 0);
    // final LN2(outtmp + x) -> fp32 d_out
    ln_k<<<M_ROWS, blk, 0, stream>>>(outtmp, x, n2w, n2b, out_main, nullptr);
}

// Round 7
// 756.276 us; speedup vs baseline: 2.8402x; 1.1454x over previous
//
#include <hip/hip_runtime.h>
#include <math.h>

typedef unsigned short ushort_t;

#define B_SZ 8
#define LSEQ 512
#define DM 768
#define DI 1536
#define DSTATE 16
#define DTRANK 48
#define M_ROWS (B_SZ * LSEQ)   // 4096

#define FLAG_SP   1
#define FLAG_CONV 2

using short8v = __attribute__((ext_vector_type(8))) short;
using float4v = __attribute__((ext_vector_type(4))) float;

__device__ __forceinline__ float us2f(ushort_t u) {
    union { unsigned int i; float f; } cv; cv.i = ((unsigned int)u) << 16; return cv.f;
}
__device__ __forceinline__ ushort_t f2bs(float f) {
    union { float f; unsigned int u; } cv; cv.f = f;
    unsigned int r = cv.u + 0x7FFFu + ((cv.u >> 16) & 1u);   // RNE
    return (ushort_t)(r >> 16);
}

// ---------------------------------------------------------------------------
// MFMA GEMM: C[4096][N] = A[4096][lda](bf16) @ Wt^T (+ b1 + b2)
//   Wt is [N][K] bf16. flags: FLAG_SP softplus; FLAG_CONV: K = 8 segs of 768,
//   seg s<7 reads A rows shifted s-3 within each L=512 slice (seg 7 plain).
// Tile TM x TN x 64, 256 thr = 2x2 waves. If Part != nullptr: split-K over
// blockIdx.z, raw fp32 partials (no bias/softplus) -> combine_k finishes.
// ---------------------------------------------------------------------------
template <int TM, int TN>
__global__ __launch_bounds__(256) void gemm_k(
    const ushort_t* __restrict__ A, int lda,
    const ushort_t* __restrict__ Wt,
    const float* __restrict__ b1, const float* __restrict__ b2,
    float* __restrict__ Cf, ushort_t* __restrict__ Cb, int ldc,
    int N, int K, int flags, int ktiles_per_z, float* __restrict__ Part)
{
    constexpr int MF = TM / 32;
    constexpr int NF = TN / 32;
    constexpr int ACPT = TM / 32;        // A k-chunks stored per thread
    constexpr int BCPT = TN / 32;
    __shared__ short Alds[8][TM][8];
    __shared__ short Blds[8][TN][8];

    const int tid  = threadIdx.x;
    const int bm   = blockIdx.x * TM;
    const int bn   = blockIdx.y * TN;
    const int wave = tid >> 6;
    const int lane = tid & 63;
    const int l16  = lane & 15;
    const int quad = lane >> 4;
    const int wm   = (wave & 1) * (TM / 2);
    const int wn   = (wave >> 1) * (TN / 2);

    const int asm_ = tid % TM;
    const int agrp = tid / TM;
    const int mg   = bm + asm_;
    const int bidx = mg >> 9;
    const int lrow = mg & 511;
    const int bsm  = tid % TN;
    const int bgrp = tid / TN;
    const int ng   = bn + bsm;
    const bool nvalid = (ng < N);

    float4v acc[MF][NF];
    #pragma unroll
    for (int i = 0; i < MF; i++)
        #pragma unroll
        for (int j = 0; j < NF; j++)
            acc[i][j] = (float4v){0.f, 0.f, 0.f, 0.f};

    const int nkt = (K + 63) >> 6;
    const int kt0 = blockIdx.z * ktiles_per_z;
    const int kt1 = min(nkt, kt0 + ktiles_per_z);
    for (int kt = kt0; kt < kt1; ++kt) {
        const int k0 = kt << 6;
        const ushort_t* arow;
        bool avalid = true;
        if (flags & FLAG_CONV) {
            const int seg  = kt / 12;
            const int koff = (kt - seg * 12) << 6;
            const int sh   = (seg < 7) ? (seg - 3) : 0;
            const int ls   = lrow + sh;
            avalid = (ls >= 0) && (ls < LSEQ);
            arow = A + (size_t)(bidx * LSEQ + (avalid ? ls : 0)) * lda + koff;
        } else {
            arow = A + (size_t)mg * lda + k0;
        }
        const ushort_t* brow = Wt + (size_t)ng * K + k0;

        #pragma unroll
        for (int i = 0; i < ACPT; i++) {
            const int c = agrp * ACPT + i;
            const bool kv = (k0 + c * 8) < K;
            short8v v = {0, 0, 0, 0, 0, 0, 0, 0};
            if (avalid && kv) v = *(const short8v*)(arow + c * 8);
            *(short8v*)(&Alds[c][asm_][0]) = v;
        }
        #pragma unroll
        for (int i = 0; i < BCPT; i++) {
            const int c = bgrp * BCPT + i;
            const bool kv = (k0 + c * 8) < K;
            short8v w = {0, 0, 0, 0, 0, 0, 0, 0};
            if (nvalid && kv) w = *(const short8v*)(brow + c * 8);
            *(short8v*)(&Blds[c][bsm][0]) = w;
        }
        __syncthreads();

        short8v a0[MF], a1[MF], b0[NF], b1v[NF];
        #pragma unroll
        for (int mi = 0; mi < MF; mi++) {
            const int ar = wm + mi * 16 + l16;
            a0[mi] = *(const short8v*)(&Alds[quad][ar][0]);
            a1[mi] = *(const short8v*)(&Alds[4 + quad][ar][0]);
        }
        #pragma unroll
        for (int ni = 0; ni < NF; ni++) {
            const int br = wn + ni * 16 + l16;
            b0[ni] = *(const short8v*)(&Blds[quad][br][0]);
            b1v[ni] = *(const short8v*)(&Blds[4 + quad][br][0]);
        }
        #pragma unroll
        for (int mi = 0; mi < MF; mi++)
            #pragma unroll
            for (int ni = 0; ni < NF; ni++) {
                acc[mi][ni] = __builtin_amdgcn_mfma_f32_16x16x32_bf16(
                    a0[mi], b0[ni], acc[mi][ni], 0, 0, 0);
                acc[mi][ni] = __builtin_amdgcn_mfma_f32_16x16x32_bf16(
                    a1[mi], b1v[ni], acc[mi][ni], 0, 0, 0);
            }
        __syncthreads();
    }

    if (Part) {
        float* P = Part + (size_t)blockIdx.z * M_ROWS * N;
        #pragma unroll
        for (int ni = 0; ni < NF; ni++) {
            const int col = bn + wn + ni * 16 + l16;
            if (col >= N) continue;
            #pragma unroll
            for (int mi = 0; mi < MF; mi++) {
                const int row0 = bm + wm + mi * 16 + quad * 4;
                #pragma unroll
                for (int r = 0; r < 4; r++)
                    P[(size_t)(row0 + r) * N + col] = acc[mi][ni][r];
            }
        }
        return;
    }

    #pragma unroll
    for (int ni = 0; ni < NF; ni++) {
        const int col = bn + wn + ni * 16 + l16;
        if (col >= N) continue;
        const float bias = (b1 ? b1[col] : 0.f) + (b2 ? b2[col] : 0.f);
        #pragma unroll
        for (int mi = 0; mi < MF; mi++) {
            const int row0 = bm + wm + mi * 16 + quad * 4;
            #pragma unroll
            for (int r = 0; r < 4; r++) {
                float v = acc[mi][ni][r] + bias;
                if (flags & FLAG_SP) v = (v > 20.f) ? v : log1pf(__expf(v));
                const size_t idx = (size_t)(row0 + r) * ldc + col;
                if (Cf) Cf[idx] = v;
                else    Cb[idx] = f2bs(v);
            }
        }
    }
}

// reduce split-K partials + bias (+softplus), write fp32 or bf16 with ldc
__global__ void combine_k(const float* __restrict__ Part, int nsplit, int N,
                          const float* __restrict__ b1, const float* __restrict__ b2,
                          float* __restrict__ Cf, ushort_t* __restrict__ Cb,
                          int ldc, int flags)
{
    int t = blockIdx.x * 256 + threadIdx.x;
    if (t >= M_ROWS * N) return;
    const int row = t / N, col = t - row * N;
    float v = 0.f;
    for (int s = 0; s < nsplit; s++) v += Part[(size_t)s * M_ROWS * N + t];
    if (b1) v += b1[col];
    if (b2) v += b2[col];
    if (flags & FLAG_SP) v = (v > 20.f) ? v : log1pf(__expf(v));
    const size_t idx = (size_t)row * ldc + col;
    if (Cf) Cf[idx] = v;
    else    Cb[idx] = f2bs(v);
}

// adj = sigmoid(nv1 @ nv2) * (1 - eye)  -> fp32
__global__ void adj_k(const float* __restrict__ nv1, const float* __restrict__ nv2,
                      float* __restrict__ out)
{
    int t = blockIdx.x * 256 + threadIdx.x;
    if (t >= 64 * 64) return;
    int i = t >> 6, j = t & 63;
    float s = 0.f;
    #pragma unroll
    for (int k = 0; k < 16; k++) s += nv1[i * 16 + k] * nv2[k * 64 + j];
    out[t] = (i == j) ? 0.f : 1.f / (1.f + __expf(-s));
}

// LayerNorm over last dim (768): LN(xin (+ addf)) * w + b -> fp32 and/or bf16
__global__ __launch_bounds__(256) void ln_k(
    const float* __restrict__ xin, const float* __restrict__ addf,
    const float* __restrict__ w, const float* __restrict__ bparam,
    float* __restrict__ outf, ushort_t* __restrict__ outb)
{
    const int r = blockIdx.x;
    const int tid = threadIdx.x;
    const size_t base = (size_t)r * DM;
    float v[3];
    float s = 0.f, ss = 0.f;
    #pragma unroll
    for (int j = 0; j < 3; j++) {
        const int c = tid + 256 * j;
        float vv = xin[base + c];
        if (addf) vv += addf[base + c];
        v[j] = vv; s += vv; ss += vv * vv;
    }
    #pragma unroll
    for (int o = 32; o > 0; o >>= 1) { s += __shfl_down(s, o); ss += __shfl_down(ss, o); }
    __shared__ float sw[4], ssw[4];
    __shared__ float mu_s, rs_s;
    const int wid = tid >> 6;
    if ((tid & 63) == 0) { sw[wid] = s; ssw[wid] = ss; }
    __syncthreads();
    if (tid == 0) {
        float st = 0.f, sst = 0.f;
        #pragma unroll
        for (int i = 0; i < 4; i++) { st += sw[i]; sst += ssw[i]; }
        const float mu = st / (float)DM;
        const float var = sst / (float)DM - mu * mu;
        mu_s = mu; rs_s = rsqrtf(fmaxf(var, 0.f) + 1e-5f);
    }
    __syncthreads();
    const float mu = mu_s, rs = rs_s;
    #pragma unroll
    for (int j = 0; j < 3; j++) {
        const int c = tid + 256 * j;
        const float o = (v[j] - mu) * rs * w[c] + bparam[c];
        if (outf) outf[base + c] = o;
        if (outb) outb[base + c] = f2bs(o);
    }
}

// tiled transpose + cvt: in fp32 [R][C] -> out bf16 [C-major]: out[c*ldout+off+r]
__global__ void tcvt_k(const float* __restrict__ in, int R, int C,
                       ushort_t* __restrict__ out, int ldout, int off)
{
    __shared__ float tile[32][33];
    const int c0 = blockIdx.x * 32, r0 = blockIdx.y * 32;
    const int tx = threadIdx.x, ty = threadIdx.y;   // (32, 8)
    #pragma unroll
    for (int j = 0; j < 4; j++) {
        const int rr = r0 + ty + j * 8;
        if (rr < R && c0 + tx < C) tile[ty + j * 8][tx] = in[(size_t)rr * C + c0 + tx];
    }
    __syncthreads();
    #pragma unroll
    for (int j = 0; j < 4; j++) {
        const int cc = c0 + ty + j * 8;
        const int kk = r0 + tx;
        if (cc < C && kk < R)
            out[(size_t)cc * ldout + off + kk] = f2bs(tile[tx][ty + j * 8]);
    }
}

// wcat_t[768][6144]: [o][seg*768+i] = conv_w[o,i,seg] (seg<7); seg7 = gcn_w[i][o]
__global__ void wcat_k(const float* __restrict__ cw, const float* __restrict__ gw,
                       ushort_t* __restrict__ out)
{
    int t = blockIdx.x * 256 + threadIdx.x;
    if (t >= DM * 8 * DM) return;
    const int o = t / (8 * DM);
    const int rr = t - o * 8 * DM;
    const int seg = rr / DM;
    const int i = rr - seg * DM;
    float v = (seg < 7) ? cw[(size_t)o * (DM * 7) + i * 7 + seg]
                        : gw[(size_t)i * DM + o];
    out[t] = f2bs(v);
}

// depthwise causal conv (D_CONV=4) + bias + silu; xz bf16 [4096][3072] (xm half)
__global__ void dwconv_k(const ushort_t* __restrict__ xz, const float* __restrict__ w,
                         const float* __restrict__ bcv, ushort_t* __restrict__ out)
{
    int t = blockIdx.x * 256 + threadIdx.x;
    if (t >= M_ROWS * DI) return;
    const int d = t % DI;
    const int bl = t / DI;
    const int l = bl & 511;
    const ushort_t* xp = xz + (size_t)bl * (2 * DI) + d;
    float s = bcv[d];
    #pragma unroll
    for (int k = 0; k < 4; k++) {
        const int ls = l + k - 3;
        if (ls >= 0) s += w[d * 4 + k] * us2f(xp[(ptrdiff_t)(k - 3) * (2 * DI)]);
    }
    out[t] = f2bs(s / (1.f + __expf(-s)));
}

// ---------------------------------------------------------------------------
// Tiled selective scan. Block 256 = 16 d x 16 n; grid (DI/16, B).
// ---------------------------------------------------------------------------
#define SDT 16
#define STL 32
__global__ __launch_bounds__(256) void scan_k(
    const float* __restrict__ dtb, ushort_t* __restrict__ xmc,
    const ushort_t* __restrict__ xdbl, const ushort_t* __restrict__ xz,
    const float* __restrict__ A_log, const float* __restrict__ Dp)
{
    __shared__ float    dt_s[STL][SDT];
    __shared__ ushort_t xm_s[STL][SDT];
    __shared__ ushort_t z_s [STL][SDT];
    __shared__ ushort_t Bv_s[STL][16];
    __shared__ ushort_t Cv_s[STL][16];
    __shared__ ushort_t y_s [STL][SDT];

    const int tid = threadIdx.x;
    const int dl  = tid >> 4;
    const int n   = tid & 15;
    const int b   = blockIdx.y;
    const int d0  = blockIdx.x * SDT;
    const int d   = d0 + dl;

    const float Ad = -__expf(A_log[d * DSTATE + n]);
    const float Dd = Dp[d];

    const float*    dtp = dtb + (size_t)b * LSEQ * DI;
    ushort_t*       xmp = xmc + (size_t)b * LSEQ * DI;
    const ushort_t* zp  = xz  + (size_t)b * LSEQ * (2 * DI) + DI;
    const ushort_t* dbp = xdbl + (size_t)b * LSEQ * 80;

    float    dt_r[2];
    ushort_t xm_r[2], z_r[2], b_r[2], c_r[2];

    auto tload = [&](int l0) {
        #pragma unroll
        for (int e = 0; e < 2; e++) {
            const int idx = tid + e * 256;
            const int ll = idx >> 4, dc = idx & 15;
            const size_t ro = (size_t)(l0 + ll);
            dt_r[e] = dtp[ro * DI + d0 + dc];
            xm_r[e] = xmp[ro * DI + d0 + dc];
            z_r[e]  = zp [ro * 2 * DI + d0 + dc];
            b_r[e]  = dbp[ro * 80 + DTRANK + dc];
            c_r[e]  = dbp[ro * 80 + DTRANK + DSTATE + dc];
        }
    };

    float h = 0.f;
    tload(0);
    for (int t = 0; t < LSEQ / STL; ++t) {
        __syncthreads();
        #pragma unroll
        for (int e = 0; e < 2; e++) {
            const int idx = tid + e * 256;
            const int ll = idx >> 4, dc = idx & 15;
            dt_s[ll][dc] = dt_r[e];
            xm_s[ll][dc] = xm_r[e];
            z_s [ll][dc] = z_r[e];
            Bv_s[ll][dc] = b_r[e];
            Cv_s[ll][dc] = c_r[e];
        }
        __syncthreads();
        if (t + 1 < LSEQ / STL) tload((t + 1) * STL);

        #pragma unroll
        for (int ll = 0; ll < STL; ++ll) {
            const float dtv = dt_s[ll][dl];
            const float xv  = us2f(xm_s[ll][dl]);
            const float Bv  = us2f(Bv_s[ll][n]);
            const float Cv  = us2f(Cv_s[ll][n]);
            h = __expf(dtv * Ad) * h + (dtv * Bv) * xv;
            float p = h * Cv;
            p += __shfl_xor(p, 1);
            p += __shfl_xor(p, 2);
            p += __shfl_xor(p, 4);
            p += __shfl_xor(p, 8);
            if (n == 0) {
                const float zv = us2f(z_s[ll][dl]);
                const float sz = zv / (1.f + __expf(-zv));
                y_s[ll][dl] = f2bs((p + Dd * xv) * sz);
            }
        }
        __syncthreads();
        #pragma unroll
        for (int e = 0; e < 2; e++) {
            const int idx = tid + e * 256;
            const int ll = idx >> 4, dc = idx & 15;
            xmp[(size_t)(t * STL + ll) * DI + d0 + dc] = y_s[ll][dc];
        }
    }
}

// fused = sigmoid(gate)*xgcn + (1-sig)*xmamba ; gcnmam = [xgcn | xmamba] bf16
__global__ void fuse_k(const ushort_t* __restrict__ gb, const ushort_t* __restrict__ gm,
                       ushort_t* __restrict__ fused)
{
    int t = blockIdx.x * 256 + threadIdx.x;
    if (t >= M_ROWS * DM) return;
    const int bl = t / DM, c = t - bl * DM;
    const float g = 1.f / (1.f + __expf(-us2f(gb[t])));
    const float xg = us2f(gm[(size_t)bl * (2 * DM) + c]);
    const float xm = us2f(gm[(size_t)bl * (2 * DM) + DM + c]);
    fused[t] = f2bs(g * xg + (1.f - g) * xm);
}

extern "C" void kernel_launch(void* const* d_in, const int* in_sizes, int n_in,
                              void* d_out, int out_size, void* d_ws, size_t ws_size,
                              hipStream_t stream)
{
    const float* x        = (const float*)d_in[0];
    const float* nv1      = (const float*)d_in[1];
    const float* nv2      = (const float*)d_in[2];
    const float* n1w      = (const float*)d_in[3];
    const float* n1b      = (const float*)d_in[4];
    const float* n2w      = (const float*)d_in[5];
    const float* n2b      = (const float*)d_in[6];
    const float* gcn_w    = (const float*)d_in[7];
    const float* gcn_b    = (const float*)d_in[8];
    const float* conv_w   = (const float*)d_in[9];
    const float* conv_b   = (const float*)d_in[10];
    const float* ggw      = (const float*)d_in[11];
    const float* ggb      = (const float*)d_in[12];
    const float* gmw      = (const float*)d_in[13];
    const float* gmb      = (const float*)d_in[14];
    const float* ow       = (const float*)d_in[15];
    const float* ob       = (const float*)d_in[16];
    const float* m_in_w   = (const float*)d_in[17];
    const float* m_conv_w = (const float*)d_in[18];
    const float* m_conv_b = (const float*)d_in[19];
    const float* m_xproj_w= (const float*)d_in[20];
    const float* m_dt_w   = (const float*)d_in[21];
    const float* m_dt_b   = (const float*)d_in[22];
    const float* m_A_log  = (const float*)d_in[23];
    const float* m_D      = (const float*)d_in[24];
    const float* m_out_w  = (const float*)d_in[25];

    float* out_main = (float*)d_out;
    float* out_adj  = out_main + (size_t)M_ROWS * DM;

    // workspace: bf16 region then fp32 region; total ~102.9 MB
    ushort_t* wsb = (ushort_t*)d_ws;
    ushort_t* xn_bf   = wsb;                       //  3,145,728
    ushort_t* xz_bf   = xn_bf   + 3145728;         // 12,582,912
    ushort_t* xmc_bf  = xz_bf   + 12582912;        //  6,291,456 (y in place)
    ushort_t* xdbl_bf = xmc_bf  + 6291456;         //    327,680
    ushort_t* gcnmam  = xdbl_bf + 327680;          //  6,291,456 [xgcn|xmamba]
    ushort_t* wcat_t  = gcnmam  + 6291456;         //  4,718,592
    ushort_t* in_w_t  = wcat_t  + 4718592;         //  2,359,296
    ushort_t* xproj_t = in_w_t  + 2359296;         //    122,880
    ushort_t* dtw_t   = xproj_t + 122880;          //     73,728
    ushort_t* outw_t  = dtw_t   + 73728;           //  1,179,648
    ushort_t* gates_t = outw_t  + 1179648;         //  1,179,648
    ushort_t* ow_t    = gates_t + 1179648;         //    589,824
    float*    dtb     = (float*)(ow_t + 589824);   //  6,291,456 fp32
    // aliases
    ushort_t* gatebuf = xz_bf;                     // (xz dead after scan)
    ushort_t* fused   = xz_bf + 3145728;
    float*    outtmp  = dtb;                       // (dtb dead after scan)
    float*    P1      = dtb;                       // conv split-K partials (2x4096x768, exact fit; dead before dt)
    float*    P2      = (float*)wcat_t;            // xproj partials (4x4096x80 = 5.2 MB < 9.4 MB; wcat dead)

    const dim3 blk(256);
    const dim3 tblk(32, 8);

    // ---- weight prep (bf16, transposed) ----
    wcat_k<<<(DM * 8 * DM + 255) / 256, blk, 0, stream>>>(conv_w, gcn_w, wcat_t);
    tcvt_k<<<dim3(3072 / 32, 768 / 32), tblk, 0, stream>>>(m_in_w, 768, 3072, in_w_t, 768, 0);
    tcvt_k<<<dim3(3, 1536 / 32), tblk, 0, stream>>>(m_xproj_w, 1536, 80, xproj_t, 1536, 0);
    tcvt_k<<<dim3(1536 / 32, 2), tblk, 0, stream>>>(m_dt_w, 48, 1536, dtw_t, 48, 0);
    tcvt_k<<<dim3(768 / 32, 1536 / 32), tblk, 0, stream>>>(m_out_w, 1536, 768, outw_t, 1536, 0);
    tcvt_k<<<dim3(768 / 32, 768 / 32), tblk, 0, stream>>>(ggw, 768, 768, gates_t, 1536, 0);
    tcvt_k<<<dim3(768 / 32, 768 / 32), tblk, 0, stream>>>(gmw, 768, 768, gates_t, 1536, 768);
    tcvt_k<<<dim3(768 / 32, 768 / 32), tblk, 0, stream>>>(ow, 768, 768, ow_t, 768, 0);

    // ---- forward ----
    adj_k<<<16, blk, 0, stream>>>(nv1, nv2, out_adj);
    ln_k<<<M_ROWS, blk, 0, stream>>>(x, nullptr, n1w, n1b, nullptr, xn_bf);

    // x_gcn (+ conv over L): split-K=2 -> P1, then combine -> gcnmam[:, 0:768]
    gemm_k<64, 64><<<dim3(64, 12, 2), blk, 0, stream>>>(
        xn_bf, DM, wcat_t, nullptr, nullptr, nullptr, nullptr, 0,
        DM, 8 * DM, FLAG_CONV, 48, P1);
    combine_k<<<(M_ROWS * DM + 255) / 256, blk, 0, stream>>>(
        P1, 2, DM, conv_b, gcn_b, nullptr, gcnmam, 2 * DM, 0);
    // xz = xn @ m_in_w -> bf16 [4096][3072]
    gemm_k<64, 128><<<dim3(64, 24, 1), blk, 0, stream>>>(
        xn_bf, DM, in_w_t, nullptr, nullptr, nullptr, xz_bf, 2 * DI,
        2 * DI, DM, 0, 1 << 20, nullptr);
    // xm = silu(dwconv(xm)) -> xmc bf16
    dwconv_k<<<(M_ROWS * DI + 255) / 256, blk, 0, stream>>>(xz_bf, m_conv_w, m_conv_b, xmc_bf);
    // x_dbl = xm @ m_xproj_w: split-K=4 -> P2, combine -> xdbl bf16 [4096][80]
    gemm_k<64, 32><<<dim3(64, 3, 4), blk, 0, stream>>>(
        xmc_bf, DI, xproj_t, nullptr, nullptr, nullptr, nullptr, 0,
        80, DI, 0, 6, P2);
    combine_k<<<(M_ROWS * 80 + 255) / 256, blk, 0, stream>>>(
        P2, 4, 80, nullptr, nullptr, nullptr, xdbl_bf, 80, 0);
    // dt = softplus(x_dbl[:, :48] @ m_dt_w + b) -> fp32
    gemm_k<64, 64><<<dim3(64, 24, 1), blk, 0, stream>>>(
        xdbl_bf, 80, dtw_t, m_dt_b, nullptr, dtb, nullptr, DI,
        DI, DTRANK, FLAG_SP, 1 << 20, nullptr);
    // selective scan -> y bf16 in place over xmc
    scan_k<<<dim3(DI / SDT, B_SZ), blk, 0, stream>>>(dtb, xmc_bf, xdbl_bf, xz_bf, m_A_log, m_D);
    // x_mamba = y @ m_out_w -> gcnmam[:, 768:1536] bf16
    gemm_k<64, 64><<<dim3(64, 12, 1), blk, 0, stream>>>(
        xmc_bf, DI, outw_t, nullptr, nullptr, nullptr, gcnmam + DM, 2 * DM,
        DM, DI, 0, 1 << 20, nullptr);
    // gate = [xgcn|xmamba] @ [ggw;gmw] + ggb + gmb -> bf16 (over dead xz)
    gemm_k<64, 64><<<dim3(64, 12, 1), blk, 0, stream>>>(
        gcnmam, 2 * DM, gates_t, ggb, gmb, nullptr, gatebuf, DM,
        DM, 2 * DM, 0, 1 << 20, nullptr);
    // fused = sig(gate)*xgcn + (1-sig)*xmamba -> bf16
    fuse_k<<<(M_ROWS * DM + 255) / 256, blk, 0, stream>>>(gatebuf, gcnmam, fused);
    // out = fused @ out_w + ob -> fp32 (over dead dtb/P1)
    gemm_k<64, 64><<<dim3(64, 12, 1), blk, 0, stream>>>(
        fused, DM, ow_t, ob, nullptr, outtmp, nullptr, DM,
        DM, DM, 0, 1 << 20, nullptr);
    // final LN2(outtmp + x) -> fp32 d_out
    ln_k<<<M_ROWS, blk, 0, stream>>>(outtmp, x, n2w, n2b, out_main, nullptr);
}

// Round 8
// 707.089 us; speedup vs baseline: 3.0378x; 1.0696x over previous
//
#include <hip/hip_runtime.h>
#include <math.h>

typedef unsigned short ushort_t;

#define B_SZ 8
#define LSEQ 512
#define DM 768
#define DI 1536
#define DSTATE 16
#define DTRANK 48
#define M_ROWS (B_SZ * LSEQ)   // 4096

#define FLAG_SP   1
#define FLAG_CONV 2

#define SEG 16          // L segments
#define SL  32          // steps per segment (SEG*SL = 512)

using short8v = __attribute__((ext_vector_type(8))) short;
using float4v = __attribute__((ext_vector_type(4))) float;

__device__ __forceinline__ float us2f(ushort_t u) {
    union { unsigned int i; float f; } cv; cv.i = ((unsigned int)u) << 16; return cv.f;
}
__device__ __forceinline__ ushort_t f2bs(float f) {
    union { float f; unsigned int u; } cv; cv.f = f;
    unsigned int r = cv.u + 0x7FFFu + ((cv.u >> 16) & 1u);   // RNE
    return (ushort_t)(r >> 16);
}

// ---------------------------------------------------------------------------
// MFMA GEMM (unchanged from R7)
// ---------------------------------------------------------------------------
template <int TM, int TN>
__global__ __launch_bounds__(256) void gemm_k(
    const ushort_t* __restrict__ A, int lda,
    const ushort_t* __restrict__ Wt,
    const float* __restrict__ b1, const float* __restrict__ b2,
    float* __restrict__ Cf, ushort_t* __restrict__ Cb, int ldc,
    int N, int K, int flags, int ktiles_per_z, float* __restrict__ Part)
{
    constexpr int MF = TM / 32;
    constexpr int NF = TN / 32;
    constexpr int ACPT = TM / 32;
    constexpr int BCPT = TN / 32;
    __shared__ short Alds[8][TM][8];
    __shared__ short Blds[8][TN][8];

    const int tid  = threadIdx.x;
    const int bm   = blockIdx.x * TM;
    const int bn   = blockIdx.y * TN;
    const int wave = tid >> 6;
    const int lane = tid & 63;
    const int l16  = lane & 15;
    const int quad = lane >> 4;
    const int wm   = (wave & 1) * (TM / 2);
    const int wn   = (wave >> 1) * (TN / 2);

    const int asm_ = tid % TM;
    const int agrp = tid / TM;
    const int mg   = bm + asm_;
    const int bidx = mg >> 9;
    const int lrow = mg & 511;
    const int bsm  = tid % TN;
    const int bgrp = tid / TN;
    const int ng   = bn + bsm;
    const bool nvalid = (ng < N);

    float4v acc[MF][NF];
    #pragma unroll
    for (int i = 0; i < MF; i++)
        #pragma unroll
        for (int j = 0; j < NF; j++)
            acc[i][j] = (float4v){0.f, 0.f, 0.f, 0.f};

    const int nkt = (K + 63) >> 6;
    const int kt0 = blockIdx.z * ktiles_per_z;
    const int kt1 = min(nkt, kt0 + ktiles_per_z);
    for (int kt = kt0; kt < kt1; ++kt) {
        const int k0 = kt << 6;
        const ushort_t* arow;
        bool avalid = true;
        if (flags & FLAG_CONV) {
            const int seg  = kt / 12;
            const int koff = (kt - seg * 12) << 6;
            const int sh   = (seg < 7) ? (seg - 3) : 0;
            const int ls   = lrow + sh;
            avalid = (ls >= 0) && (ls < LSEQ);
            arow = A + (size_t)(bidx * LSEQ + (avalid ? ls : 0)) * lda + koff;
        } else {
            arow = A + (size_t)mg * lda + k0;
        }
        const ushort_t* brow = Wt + (size_t)ng * K + k0;

        #pragma unroll
        for (int i = 0; i < ACPT; i++) {
            const int c = agrp * ACPT + i;
            const bool kv = (k0 + c * 8) < K;
            short8v v = {0, 0, 0, 0, 0, 0, 0, 0};
            if (avalid && kv) v = *(const short8v*)(arow + c * 8);
            *(short8v*)(&Alds[c][asm_][0]) = v;
        }
        #pragma unroll
        for (int i = 0; i < BCPT; i++) {
            const int c = bgrp * BCPT + i;
            const bool kv = (k0 + c * 8) < K;
            short8v w = {0, 0, 0, 0, 0, 0, 0, 0};
            if (nvalid && kv) w = *(const short8v*)(brow + c * 8);
            *(short8v*)(&Blds[c][bsm][0]) = w;
        }
        __syncthreads();

        short8v a0[MF], a1[MF], b0[NF], b1v[NF];
        #pragma unroll
        for (int mi = 0; mi < MF; mi++) {
            const int ar = wm + mi * 16 + l16;
            a0[mi] = *(const short8v*)(&Alds[quad][ar][0]);
            a1[mi] = *(const short8v*)(&Alds[4 + quad][ar][0]);
        }
        #pragma unroll
        for (int ni = 0; ni < NF; ni++) {
            const int br = wn + ni * 16 + l16;
            b0[ni] = *(const short8v*)(&Blds[quad][br][0]);
            b1v[ni] = *(const short8v*)(&Blds[4 + quad][br][0]);
        }
        #pragma unroll
        for (int mi = 0; mi < MF; mi++)
            #pragma unroll
            for (int ni = 0; ni < NF; ni++) {
                acc[mi][ni] = __builtin_amdgcn_mfma_f32_16x16x32_bf16(
                    a0[mi], b0[ni], acc[mi][ni], 0, 0, 0);
                acc[mi][ni] = __builtin_amdgcn_mfma_f32_16x16x32_bf16(
                    a1[mi], b1v[ni], acc[mi][ni], 0, 0, 0);
            }
        __syncthreads();
    }

    if (Part) {
        float* P = Part + (size_t)blockIdx.z * M_ROWS * N;
        #pragma unroll
        for (int ni = 0; ni < NF; ni++) {
            const int col = bn + wn + ni * 16 + l16;
            if (col >= N) continue;
            #pragma unroll
            for (int mi = 0; mi < MF; mi++) {
                const int row0 = bm + wm + mi * 16 + quad * 4;
                #pragma unroll
                for (int r = 0; r < 4; r++)
                    P[(size_t)(row0 + r) * N + col] = acc[mi][ni][r];
            }
        }
        return;
    }

    #pragma unroll
    for (int ni = 0; ni < NF; ni++) {
        const int col = bn + wn + ni * 16 + l16;
        if (col >= N) continue;
        const float bias = (b1 ? b1[col] : 0.f) + (b2 ? b2[col] : 0.f);
        #pragma unroll
        for (int mi = 0; mi < MF; mi++) {
            const int row0 = bm + wm + mi * 16 + quad * 4;
            #pragma unroll
            for (int r = 0; r < 4; r++) {
                float v = acc[mi][ni][r] + bias;
                if (flags & FLAG_SP) v = (v > 20.f) ? v : log1pf(__expf(v));
                const size_t idx = (size_t)(row0 + r) * ldc + col;
                if (Cf) Cf[idx] = v;
                else    Cb[idx] = f2bs(v);
            }
        }
    }
}

// reduce split-K partials + bias (+softplus)
__global__ void combine_k(const float* __restrict__ Part, int nsplit, int N,
                          const float* __restrict__ b1, const float* __restrict__ b2,
                          float* __restrict__ Cf, ushort_t* __restrict__ Cb,
                          int ldc, int flags)
{
    int t = blockIdx.x * 256 + threadIdx.x;
    if (t >= M_ROWS * N) return;
    const int row = t / N, col = t - row * N;
    float v = 0.f;
    for (int s = 0; s < nsplit; s++) v += Part[(size_t)s * M_ROWS * N + t];
    if (b1) v += b1[col];
    if (b2) v += b2[col];
    if (flags & FLAG_SP) v = (v > 20.f) ? v : log1pf(__expf(v));
    const size_t idx = (size_t)row * ldc + col;
    if (Cf) Cf[idx] = v;
    else    Cb[idx] = f2bs(v);
}

// adj = sigmoid(nv1 @ nv2) * (1 - eye)  -> fp32
__global__ void adj_k(const float* __restrict__ nv1, const float* __restrict__ nv2,
                      float* __restrict__ out)
{
    int t = blockIdx.x * 256 + threadIdx.x;
    if (t >= 64 * 64) return;
    int i = t >> 6, j = t & 63;
    float s = 0.f;
    #pragma unroll
    for (int k = 0; k < 16; k++) s += nv1[i * 16 + k] * nv2[k * 64 + j];
    out[t] = (i == j) ? 0.f : 1.f / (1.f + __expf(-s));
}

// LayerNorm over last dim (768)
__global__ __launch_bounds__(256) void ln_k(
    const float* __restrict__ xin, const float* __restrict__ addf,
    const float* __restrict__ w, const float* __restrict__ bparam,
    float* __restrict__ outf, ushort_t* __restrict__ outb)
{
    const int r = blockIdx.x;
    const int tid = threadIdx.x;
    const size_t base = (size_t)r * DM;
    float v[3];
    float s = 0.f, ss = 0.f;
    #pragma unroll
    for (int j = 0; j < 3; j++) {
        const int c = tid + 256 * j;
        float vv = xin[base + c];
        if (addf) vv += addf[base + c];
        v[j] = vv; s += vv; ss += vv * vv;
    }
    #pragma unroll
    for (int o = 32; o > 0; o >>= 1) { s += __shfl_down(s, o); ss += __shfl_down(ss, o); }
    __shared__ float sw[4], ssw[4];
    __shared__ float mu_s, rs_s;
    const int wid = tid >> 6;
    if ((tid & 63) == 0) { sw[wid] = s; ssw[wid] = ss; }
    __syncthreads();
    if (tid == 0) {
        float st = 0.f, sst = 0.f;
        #pragma unroll
        for (int i = 0; i < 4; i++) { st += sw[i]; sst += ssw[i]; }
        const float mu = st / (float)DM;
        const float var = sst / (float)DM - mu * mu;
        mu_s = mu; rs_s = rsqrtf(fmaxf(var, 0.f) + 1e-5f);
    }
    __syncthreads();
    const float mu = mu_s, rs = rs_s;
    #pragma unroll
    for (int j = 0; j < 3; j++) {
        const int c = tid + 256 * j;
        const float o = (v[j] - mu) * rs * w[c] + bparam[c];
        if (outf) outf[base + c] = o;
        if (outb) outb[base + c] = f2bs(o);
    }
}

// tiled transpose + cvt: fp32 [R][C] -> bf16 out[c*ldout+off+r]
__global__ void tcvt_k(const float* __restrict__ in, int R, int C,
                       ushort_t* __restrict__ out, int ldout, int off)
{
    __shared__ float tile[32][33];
    const int c0 = blockIdx.x * 32, r0 = blockIdx.y * 32;
    const int tx = threadIdx.x, ty = threadIdx.y;   // (32, 8)
    #pragma unroll
    for (int j = 0; j < 4; j++) {
        const int rr = r0 + ty + j * 8;
        if (rr < R && c0 + tx < C) tile[ty + j * 8][tx] = in[(size_t)rr * C + c0 + tx];
    }
    __syncthreads();
    #pragma unroll
    for (int j = 0; j < 4; j++) {
        const int cc = c0 + ty + j * 8;
        const int kk = r0 + tx;
        if (cc < C && kk < R)
            out[(size_t)cc * ldout + off + kk] = f2bs(tile[tx][ty + j * 8]);
    }
}

// wcat_t[768][6144]
__global__ void wcat_k(const float* __restrict__ cw, const float* __restrict__ gw,
                       ushort_t* __restrict__ out)
{
    int t = blockIdx.x * 256 + threadIdx.x;
    if (t >= DM * 8 * DM) return;
    const int o = t / (8 * DM);
    const int rr = t - o * 8 * DM;
    const int seg = rr / DM;
    const int i = rr - seg * DM;
    float v = (seg < 7) ? cw[(size_t)o * (DM * 7) + i * 7 + seg]
                        : gw[(size_t)i * DM + o];
    out[t] = f2bs(v);
}

// depthwise causal conv + bias + silu
__global__ void dwconv_k(const ushort_t* __restrict__ xz, const float* __restrict__ w,
                         const float* __restrict__ bcv, ushort_t* __restrict__ out)
{
    int t = blockIdx.x * 256 + threadIdx.x;
    if (t >= M_ROWS * DI) return;
    const int d = t % DI;
    const int bl = t / DI;
    const int l = bl & 511;
    const ushort_t* xp = xz + (size_t)bl * (2 * DI) + d;
    float s = bcv[d];
    #pragma unroll
    for (int k = 0; k < 4; k++) {
        const int ls = l + k - 3;
        if (ls >= 0) s += w[d * 4 + k] * us2f(xp[(ptrdiff_t)(k - 3) * (2 * DI)]);
    }
    out[t] = f2bs(s / (1.f + __expf(-s)));
}

// ---------------------------------------------------------------------------
// Segmented selective scan, n-states in registers, no cross-lane ops.
// Grid (DI/256, B, SEG); 256 thr, thread = one d.
// Pass A: per segment compute A_seg[n]=prod(a), B_seg[n]=local scan (h0=0).
// Pass B: reconstitute h0 from prior segments' (A,B), recompute, emit y.
// ---------------------------------------------------------------------------
__global__ __launch_bounds__(256) void scan_a_k(
    const float* __restrict__ dtb, const ushort_t* __restrict__ xmc,
    const ushort_t* __restrict__ xdbl, const float* __restrict__ A_log,
    ushort_t* __restrict__ Aseg, float* __restrict__ Bseg)
{
    __shared__ ushort_t B_s[SL][16];
    const int tid = threadIdx.x;
    const int d   = blockIdx.x * 256 + tid;
    const int b   = blockIdx.y;
    const int sg  = blockIdx.z;
    const int l0  = sg * SL;

    const ushort_t* dbp = xdbl + ((size_t)b * LSEQ + l0) * 80;
    #pragma unroll
    for (int e = 0; e < 2; e++) {
        const int idx = tid + e * 256;
        const int ll = idx >> 4, n = idx & 15;
        B_s[ll][n] = dbp[(size_t)ll * 80 + DTRANK + n];
    }

    float Ad[16], h[16], Ap[16];
    #pragma unroll
    for (int n = 0; n < 16; n++) {
        Ad[n] = -__expf(A_log[(size_t)d * DSTATE + n]);
        h[n] = 0.f; Ap[n] = 1.f;
    }
    const float*    dtp = dtb + ((size_t)b * LSEQ + l0) * DI + d;
    const ushort_t* xp  = xmc + ((size_t)b * LSEQ + l0) * DI + d;
    __syncthreads();

    for (int l = 0; l < SL; ++l) {
        const float dtv = dtp[(size_t)l * DI];
        const float dx  = dtv * us2f(xp[(size_t)l * DI]);
        #pragma unroll
        for (int n = 0; n < 16; n++) {
            const float a = __expf(dtv * Ad[n]);
            h[n] = a * h[n] + us2f(B_s[l][n]) * dx;
            Ap[n] *= a;
        }
    }
    #pragma unroll
    for (int n = 0; n < 16; n++) {
        const size_t o = ((size_t)(b * SEG + sg) * 16 + n) * DI + d;
        Aseg[o] = f2bs(Ap[n]);
        Bseg[o] = h[n];
    }
}

__global__ __launch_bounds__(256) void scan_b_k(
    const float* __restrict__ dtb, ushort_t* __restrict__ xmc,
    const ushort_t* __restrict__ xdbl, const ushort_t* __restrict__ xz,
    const float* __restrict__ A_log, const float* __restrict__ Dp,
    const ushort_t* __restrict__ Aseg, const float* __restrict__ Bseg)
{
    __shared__ ushort_t B_s[SL][16];
    __shared__ ushort_t C_s[SL][16];
    const int tid = threadIdx.x;
    const int d   = blockIdx.x * 256 + tid;
    const int b   = blockIdx.y;
    const int sg  = blockIdx.z;
    const int l0  = sg * SL;

    const ushort_t* dbp = xdbl + ((size_t)b * LSEQ + l0) * 80;
    #pragma unroll
    for (int e = 0; e < 2; e++) {
        const int idx = tid + e * 256;
        const int ll = idx >> 4, n = idx & 15;
        B_s[ll][n] = dbp[(size_t)ll * 80 + DTRANK + n];
        C_s[ll][n] = dbp[(size_t)ll * 80 + DTRANK + DSTATE + n];
    }

    float Ad[16], h[16];
    #pragma unroll
    for (int n = 0; n < 16; n++) {
        Ad[n] = -__expf(A_log[(size_t)d * DSTATE + n]);
        h[n] = 0.f;
    }
    // reconstitute h0 = carry of segments 0..sg-1
    for (int s = 0; s < sg; ++s) {
        #pragma unroll
        for (int n = 0; n < 16; n++) {
            const size_t o = ((size_t)(b * SEG + s) * 16 + n) * DI + d;
            h[n] = us2f(Aseg[o]) * h[n] + Bseg[o];
        }
    }
    const float Dd = Dp[d];
    const float*    dtp = dtb + ((size_t)b * LSEQ + l0) * DI + d;
    ushort_t*       xp  = xmc + ((size_t)b * LSEQ + l0) * DI + d;
    const ushort_t* zp  = xz  + ((size_t)b * LSEQ + l0) * (2 * DI) + DI + d;
    __syncthreads();

    for (int l = 0; l < SL; ++l) {
        const float dtv = dtp[(size_t)l * DI];
        const float xv  = us2f(xp[(size_t)l * DI]);
        const float dx  = dtv * xv;
        float p = 0.f;
        #pragma unroll
        for (int n = 0; n < 16; n++) {
            const float a = __expf(dtv * Ad[n]);
            h[n] = a * h[n] + us2f(B_s[l][n]) * dx;
            p += h[n] * us2f(C_s[l][n]);
        }
        const float zv = us2f(zp[(size_t)l * 2 * DI]);
        const float sz = zv / (1.f + __expf(-zv));
        xp[(size_t)l * DI] = f2bs((p + Dd * xv) * sz);
    }
}

// fused = sigmoid(gate)*xgcn + (1-sig)*xmamba
__global__ void fuse_k(const ushort_t* __restrict__ gb, const ushort_t* __restrict__ gm,
                       ushort_t* __restrict__ fused)
{
    int t = blockIdx.x * 256 + threadIdx.x;
    if (t >= M_ROWS * DM) return;
    const int bl = t / DM, c = t - bl * DM;
    const float g = 1.f / (1.f + __expf(-us2f(gb[t])));
    const float xg = us2f(gm[(size_t)bl * (2 * DM) + c]);
    const float xm = us2f(gm[(size_t)bl * (2 * DM) + DM + c]);
    fused[t] = f2bs(g * xg + (1.f - g) * xm);
}

extern "C" void kernel_launch(void* const* d_in, const int* in_sizes, int n_in,
                              void* d_out, int out_size, void* d_ws, size_t ws_size,
                              hipStream_t stream)
{
    const float* x        = (const float*)d_in[0];
    const float* nv1      = (const float*)d_in[1];
    const float* nv2      = (const float*)d_in[2];
    const float* n1w      = (const float*)d_in[3];
    const float* n1b      = (const float*)d_in[4];
    const float* n2w      = (const float*)d_in[5];
    const float* n2b      = (const float*)d_in[6];
    const float* gcn_w    = (const float*)d_in[7];
    const float* gcn_b    = (const float*)d_in[8];
    const float* conv_w   = (const float*)d_in[9];
    const float* conv_b   = (const float*)d_in[10];
    const float* ggw      = (const float*)d_in[11];
    const float* ggb      = (const float*)d_in[12];
    const float* gmw      = (const float*)d_in[13];
    const float* gmb      = (const float*)d_in[14];
    const float* ow       = (const float*)d_in[15];
    const float* ob       = (const float*)d_in[16];
    const float* m_in_w   = (const float*)d_in[17];
    const float* m_conv_w = (const float*)d_in[18];
    const float* m_conv_b = (const float*)d_in[19];
    const float* m_xproj_w= (const float*)d_in[20];
    const float* m_dt_w   = (const float*)d_in[21];
    const float* m_dt_b   = (const float*)d_in[22];
    const float* m_A_log  = (const float*)d_in[23];
    const float* m_D      = (const float*)d_in[24];
    const float* m_out_w  = (const float*)d_in[25];

    float* out_main = (float*)d_out;
    float* out_adj  = out_main + (size_t)M_ROWS * DM;

    // workspace layout (~102.9 MB)
    ushort_t* wsb = (ushort_t*)d_ws;
    ushort_t* xn_bf   = wsb;                       //  3,145,728
    ushort_t* xz_bf   = xn_bf   + 3145728;         // 12,582,912
    ushort_t* xmc_bf  = xz_bf   + 12582912;        //  6,291,456 (y in place)
    ushort_t* xdbl_bf = xmc_bf  + 6291456;         //    327,680
    ushort_t* gcnmam  = xdbl_bf + 327680;          //  6,291,456 [xgcn|xmamba]
    ushort_t* wcat_t  = gcnmam  + 6291456;         //  4,718,592
    ushort_t* in_w_t  = wcat_t  + 4718592;         //  2,359,296
    ushort_t* xproj_t = in_w_t  + 2359296;         //    122,880
    ushort_t* dtw_t   = xproj_t + 122880;          //     73,728
    ushort_t* outw_t  = dtw_t   + 73728;           //  1,179,648
    ushort_t* gates_t = outw_t  + 1179648;         //  1,179,648
    ushort_t* ow_t    = gates_t + 1179648;         //    589,824
    float*    dtb     = (float*)(ow_t + 589824);   //  6,291,456 fp32
    // aliases
    ushort_t* gatebuf = xz_bf;                     // xz dead after scan
    ushort_t* fused   = xz_bf + 3145728;
    float*    outtmp  = dtb;                       // dtb dead after scan
    float*    P1      = dtb;                       // conv split-K partials
    float*    P2      = (float*)wcat_t;            // xproj partials (pre-scan)
    ushort_t* Aseg    = xn_bf;                     // 3,145,728 bf16 (xn dead)
    float*    Bseg    = (float*)wcat_t;            // 3,145,728 fp32 (wcat+in_w dead)

    const dim3 blk(256);
    const dim3 tblk(32, 8);

    // ---- weight prep (bf16, transposed) ----
    wcat_k<<<(DM * 8 * DM + 255) / 256, blk, 0, stream>>>(conv_w, gcn_w, wcat_t);
    tcvt_k<<<dim3(3072 / 32, 768 / 32), tblk, 0, stream>>>(m_in_w, 768, 3072, in_w_t, 768, 0);
    tcvt_k<<<dim3(3, 1536 / 32), tblk, 0, stream>>>(m_xproj_w, 1536, 80, xproj_t, 1536, 0);
    tcvt_k<<<dim3(1536 / 32, 2), tblk, 0, stream>>>(m_dt_w, 48, 1536, dtw_t, 48, 0);
    tcvt_k<<<dim3(768 / 32, 1536 / 32), tblk, 0, stream>>>(m_out_w, 1536, 768, outw_t, 1536, 0);
    tcvt_k<<<dim3(768 / 32, 768 / 32), tblk, 0, stream>>>(ggw, 768, 768, gates_t, 1536, 0);
    tcvt_k<<<dim3(768 / 32, 768 / 32), tblk, 0, stream>>>(gmw, 768, 768, gates_t, 1536, 768);
    tcvt_k<<<dim3(768 / 32, 768 / 32), tblk, 0, stream>>>(ow, 768, 768, ow_t, 768, 0);

    // ---- forward ----
    adj_k<<<16, blk, 0, stream>>>(nv1, nv2, out_adj);
    ln_k<<<M_ROWS, blk, 0, stream>>>(x, nullptr, n1w, n1b, nullptr, xn_bf);

    // x_gcn (+ conv over L): split-K=2 -> P1 -> combine -> gcnmam[:, 0:768]
    gemm_k<64, 64><<<dim3(64, 12, 2), blk, 0, stream>>>(
        xn_bf, DM, wcat_t, nullptr, nullptr, nullptr, nullptr, 0,
        DM, 8 * DM, FLAG_CONV, 48, P1);
    combine_k<<<(M_ROWS * DM + 255) / 256, blk, 0, stream>>>(
        P1, 2, DM, conv_b, gcn_b, nullptr, gcnmam, 2 * DM, 0);
    // xz = xn @ m_in_w -> bf16 [4096][3072]
    gemm_k<64, 128><<<dim3(64, 24, 1), blk, 0, stream>>>(
        xn_bf, DM, in_w_t, nullptr, nullptr, nullptr, xz_bf, 2 * DI,
        2 * DI, DM, 0, 1 << 20, nullptr);
    // xm = silu(dwconv(xm)) -> xmc bf16
    dwconv_k<<<(M_ROWS * DI + 255) / 256, blk, 0, stream>>>(xz_bf, m_conv_w, m_conv_b, xmc_bf);
    // x_dbl = xm @ m_xproj_w: split-K=4 -> P2 -> combine -> xdbl bf16
    gemm_k<64, 32><<<dim3(64, 3, 4), blk, 0, stream>>>(
        xmc_bf, DI, xproj_t, nullptr, nullptr, nullptr, nullptr, 0,
        80, DI, 0, 6, P2);
    combine_k<<<(M_ROWS * 80 + 255) / 256, blk, 0, stream>>>(
        P2, 4, 80, nullptr, nullptr, nullptr, xdbl_bf, 80, 0);
    // dt = softplus(x_dbl[:, :48] @ m_dt_w + b) -> fp32
    gemm_k<64, 64><<<dim3(64, 24, 1), blk, 0, stream>>>(
        xdbl_bf, 80, dtw_t, m_dt_b, nullptr, dtb, nullptr, DI,
        DI, DTRANK, FLAG_SP, 1 << 20, nullptr);
    // segmented selective scan -> y bf16 in place over xmc
    scan_a_k<<<dim3(DI / 256, B_SZ, SEG), blk, 0, stream>>>(
        dtb, xmc_bf, xdbl_bf, m_A_log, Aseg, Bseg);
    scan_b_k<<<dim3(DI / 256, B_SZ, SEG), blk, 0, stream>>>(
        dtb, xmc_bf, xdbl_bf, xz_bf, m_A_log, m_D, Aseg, Bseg);
    // x_mamba = y @ m_out_w -> gcnmam[:, 768:1536]
    gemm_k<64, 64><<<dim3(64, 12, 1), blk, 0, stream>>>(
        xmc_bf, DI, outw_t, nullptr, nullptr, nullptr, gcnmam + DM, 2 * DM,
        DM, DI, 0, 1 << 20, nullptr);
    // gate = [xgcn|xmamba] @ [ggw;gmw] + ggb + gmb -> bf16 (over dead xz)
    gemm_k<64, 64><<<dim3(64, 12, 1), blk, 0, stream>>>(
        gcnmam, 2 * DM, gates_t, ggb, gmb, nullptr, gatebuf, DM,
        DM, 2 * DM, 0, 1 << 20, nullptr);
    // fused = sig(gate)*xgcn + (1-sig)*xmamba -> bf16
    fuse_k<<<(M_ROWS * DM + 255) / 256, blk, 0, stream>>>(gatebuf, gcnmam, fused);
    // out = fused @ out_w + ob -> fp32 (over dead dtb/P1)
    gemm_k<64, 64><<<dim3(64, 12, 1), blk, 0, stream>>>(
        fused, DM, ow_t, ob, nullptr, outtmp, nullptr, DM,
        DM, DM, 0, 1 << 20, nullptr);
    // final LN2(outtmp + x) -> fp32 d_out
    ln_k<<<M_ROWS, blk, 0, stream>>>(outtmp, x, n2w, n2b, out_main, nullptr);
}

// Round 9
// 656.589 us; speedup vs baseline: 3.2714x; 1.0769x over previous
//
#include <hip/hip_runtime.h>
#include <math.h>

typedef unsigned short ushort_t;

#define B_SZ 8
#define LSEQ 512
#define DM 768
#define DI 1536
#define DSTATE 16
#define DTRANK 48
#define M_ROWS (B_SZ * LSEQ)   // 4096

#define FLAG_SP   1
#define FLAG_CONV 2
#define FLAG_FUSE 4

#define SEG 16
#define SL  32

using short8v = __attribute__((ext_vector_type(8))) short;
using float4v = __attribute__((ext_vector_type(4))) float;

#define AS1(p) ((const __attribute__((address_space(1))) void*)(p))
#define AS3(p) ((__attribute__((address_space(3))) void*)(p))

__device__ __forceinline__ float us2f(ushort_t u) {
    union { unsigned int i; float f; } cv; cv.i = ((unsigned int)u) << 16; return cv.f;
}
__device__ __forceinline__ ushort_t f2bs(float f) {
    union { float f; unsigned int u; } cv; cv.f = f;
    unsigned int r = cv.u + 0x7FFFu + ((cv.u >> 16) & 1u);   // RNE
    return (ushort_t)(r >> 16);
}

// ---------------------------------------------------------------------------
// MFMA GEMM with direct global->LDS (width=16) staging.
// C[4096][N] = A[4096][lda](bf16) @ Wt^T (+b1+b2); Wt is [N][K] bf16.
// LDS chunk-major: flat slot s=(c*T + r), 16B per slot -> global_load_lds
// dest = base + lane*16 matches slot order exactly. OOB lanes load a zeroed
// page instead (exact zeros, no divergence).
// ---------------------------------------------------------------------------
template <int TM, int TN>
__global__ __launch_bounds__(256) void gemm_k(
    const ushort_t* __restrict__ A, int lda,
    const ushort_t* __restrict__ Wt,
    const float* __restrict__ b1, const float* __restrict__ b2,
    float* __restrict__ Cf, ushort_t* __restrict__ Cb, int ldc,
    int N, int K, int flags, int ktiles_per_z, float* __restrict__ Part,
    const ushort_t* __restrict__ zpage, const ushort_t* __restrict__ Gm)
{
    constexpr int MF = TM / 32;
    constexpr int NF = TN / 32;
    constexpr int AI = TM / 32;      // A 16B-issues per wave (8*TM/64/4)
    constexpr int BI = TN / 32;
    __shared__ short Alds[8 * TM * 8];
    __shared__ short Blds[8 * TN * 8];

    const int tid  = threadIdx.x;
    const int wave = tid >> 6;
    const int lane = tid & 63;
    const int l16  = lane & 15;
    const int quad = lane >> 4;
    const int bm   = blockIdx.x * TM;
    const int bn   = blockIdx.y * TN;
    const int wm   = (wave & 1) * (TM / 2);
    const int wn   = (wave >> 1) * (TN / 2);

    float4v acc[MF][NF];
    #pragma unroll
    for (int i = 0; i < MF; i++)
        #pragma unroll
        for (int j = 0; j < NF; j++)
            acc[i][j] = (float4v){0.f, 0.f, 0.f, 0.f};

    const int nkt = (K + 63) >> 6;
    const int kt0 = blockIdx.z * ktiles_per_z;
    const int kt1 = min(nkt, kt0 + ktiles_per_z);
    for (int kt = kt0; kt < kt1; ++kt) {
        const int k0 = kt << 6;
        int koff = k0, sh = 0;
        if (flags & FLAG_CONV) {
            const int seg = kt / 12;
            koff = (kt - seg * 12) << 6;
            sh = (seg < 7) ? (seg - 3) : 0;
        }
        // A staging
        #pragma unroll
        for (int i = 0; i < AI; i++) {
            const int j = wave * AI + i;
            const int slot = j * 64 + lane;
            const int c = slot / TM, r = slot % TM;
            const int mg = bm + r;
            const ushort_t* gp = zpage;
            if (flags & FLAG_CONV) {
                const int ls = (mg & 511) + sh;
                if (ls >= 0 && ls < LSEQ)
                    gp = A + (size_t)((mg >> 9) * LSEQ + ls) * lda + koff + c * 8;
            } else {
                if (k0 + c * 8 < K)
                    gp = A + (size_t)mg * lda + k0 + c * 8;
            }
            __builtin_amdgcn_global_load_lds(AS1(gp), AS3(Alds + j * 512), 16, 0, 0);
        }
        // B staging
        #pragma unroll
        for (int i = 0; i < BI; i++) {
            const int j = wave * BI + i;
            const int slot = j * 64 + lane;
            const int c = slot / TN, r = slot % TN;
            const int ng = bn + r;
            const ushort_t* gp = zpage;
            if (ng < N && (k0 + c * 8) < K)
                gp = Wt + (size_t)ng * K + k0 + c * 8;
            __builtin_amdgcn_global_load_lds(AS1(gp), AS3(Blds + j * 512), 16, 0, 0);
        }
        __syncthreads();

        short8v a0[MF], a1[MF], b0[NF], b1v[NF];
        #pragma unroll
        for (int mi = 0; mi < MF; mi++) {
            const int ar = wm + mi * 16 + l16;
            a0[mi] = *(const short8v*)(Alds + ((size_t)quad * TM + ar) * 8);
            a1[mi] = *(const short8v*)(Alds + ((size_t)(4 + quad) * TM + ar) * 8);
        }
        #pragma unroll
        for (int ni = 0; ni < NF; ni++) {
            const int br = wn + ni * 16 + l16;
            b0[ni] = *(const short8v*)(Blds + ((size_t)quad * TN + br) * 8);
            b1v[ni] = *(const short8v*)(Blds + ((size_t)(4 + quad) * TN + br) * 8);
        }
        #pragma unroll
        for (int mi = 0; mi < MF; mi++)
            #pragma unroll
            for (int ni = 0; ni < NF; ni++) {
                acc[mi][ni] = __builtin_amdgcn_mfma_f32_16x16x32_bf16(
                    a0[mi], b0[ni], acc[mi][ni], 0, 0, 0);
                acc[mi][ni] = __builtin_amdgcn_mfma_f32_16x16x32_bf16(
                    a1[mi], b1v[ni], acc[mi][ni], 0, 0, 0);
            }
        __syncthreads();
    }

    if (Part) {
        float* P = Part + (size_t)blockIdx.z * M_ROWS * N;
        #pragma unroll
        for (int ni = 0; ni < NF; ni++) {
            const int col = bn + wn + ni * 16 + l16;
            if (col >= N) continue;
            #pragma unroll
            for (int mi = 0; mi < MF; mi++) {
                const int row0 = bm + wm + mi * 16 + quad * 4;
                #pragma unroll
                for (int r = 0; r < 4; r++)
                    P[(size_t)(row0 + r) * N + col] = acc[mi][ni][r];
            }
        }
        return;
    }

    #pragma unroll
    for (int ni = 0; ni < NF; ni++) {
        const int col = bn + wn + ni * 16 + l16;
        if (col >= N) continue;
        const float bias = (b1 ? b1[col] : 0.f) + (b2 ? b2[col] : 0.f);
        #pragma unroll
        for (int mi = 0; mi < MF; mi++) {
            const int row0 = bm + wm + mi * 16 + quad * 4;
            #pragma unroll
            for (int r = 0; r < 4; r++) {
                float v = acc[mi][ni][r] + bias;
                const int row = row0 + r;
                if (flags & FLAG_FUSE) {
                    const float g = 1.f / (1.f + __expf(-v));
                    const float xg = us2f(Gm[(size_t)row * (2 * DM) + col]);
                    const float xm = us2f(Gm[(size_t)row * (2 * DM) + DM + col]);
                    Cb[(size_t)row * ldc + col] = f2bs(g * xg + (1.f - g) * xm);
                    continue;
                }
                if (flags & FLAG_SP) v = (v > 20.f) ? v : log1pf(__expf(v));
                const size_t idx = (size_t)row * ldc + col;
                if (Cf) Cf[idx] = v;
                else    Cb[idx] = f2bs(v);
            }
        }
    }
}

// reduce split-K partials + bias (+softplus)
__global__ void combine_k(const float* __restrict__ Part, int nsplit, int N,
                          const float* __restrict__ b1, const float* __restrict__ b2,
                          float* __restrict__ Cf, ushort_t* __restrict__ Cb,
                          int ldc, int flags)
{
    int t = blockIdx.x * 256 + threadIdx.x;
    if (t >= M_ROWS * N) return;
    const int row = t / N, col = t - row * N;
    float v = 0.f;
    for (int s = 0; s < nsplit; s++) v += Part[(size_t)s * M_ROWS * N + t];
    if (b1) v += b1[col];
    if (b2) v += b2[col];
    if (flags & FLAG_SP) v = (v > 20.f) ? v : log1pf(__expf(v));
    const size_t idx = (size_t)row * ldc + col;
    if (Cf) Cf[idx] = v;
    else    Cb[idx] = f2bs(v);
}

// adj = sigmoid(nv1 @ nv2) * (1 - eye)  -> fp32
__global__ void adj_k(const float* __restrict__ nv1, const float* __restrict__ nv2,
                      float* __restrict__ out)
{
    int t = blockIdx.x * 256 + threadIdx.x;
    if (t >= 64 * 64) return;
    int i = t >> 6, j = t & 63;
    float s = 0.f;
    #pragma unroll
    for (int k = 0; k < 16; k++) s += nv1[i * 16 + k] * nv2[k * 64 + j];
    out[t] = (i == j) ? 0.f : 1.f / (1.f + __expf(-s));
}

// LayerNorm over last dim (768)
__global__ __launch_bounds__(256) void ln_k(
    const float* __restrict__ xin, const float* __restrict__ addf,
    const float* __restrict__ w, const float* __restrict__ bparam,
    float* __restrict__ outf, ushort_t* __restrict__ outb)
{
    const int r = blockIdx.x;
    const int tid = threadIdx.x;
    const size_t base = (size_t)r * DM;
    float v[3];
    float s = 0.f, ss = 0.f;
    #pragma unroll
    for (int j = 0; j < 3; j++) {
        const int c = tid + 256 * j;
        float vv = xin[base + c];
        if (addf) vv += addf[base + c];
        v[j] = vv; s += vv; ss += vv * vv;
    }
    #pragma unroll
    for (int o = 32; o > 0; o >>= 1) { s += __shfl_down(s, o); ss += __shfl_down(ss, o); }
    __shared__ float sw[4], ssw[4];
    __shared__ float mu_s, rs_s;
    const int wid = tid >> 6;
    if ((tid & 63) == 0) { sw[wid] = s; ssw[wid] = ss; }
    __syncthreads();
    if (tid == 0) {
        float st = 0.f, sst = 0.f;
        #pragma unroll
        for (int i = 0; i < 4; i++) { st += sw[i]; sst += ssw[i]; }
        const float mu = st / (float)DM;
        const float var = sst / (float)DM - mu * mu;
        mu_s = mu; rs_s = rsqrtf(fmaxf(var, 0.f) + 1e-5f);
    }
    __syncthreads();
    const float mu = mu_s, rs = rs_s;
    #pragma unroll
    for (int j = 0; j < 3; j++) {
        const int c = tid + 256 * j;
        const float o = (v[j] - mu) * rs * w[c] + bparam[c];
        if (outf) outf[base + c] = o;
        if (outb) outb[base + c] = f2bs(o);
    }
}

// batched tiled transpose+cvt: 7 descriptors, flat tile index
struct TDesc { const float* in; ushort_t* out; int R, C, ldout, off, tile0; };
struct TPack { TDesc d[7]; };
__global__ void tcvt7_k(TPack p)
{
    __shared__ float tile[32][33];
    int di = 0;
    #pragma unroll
    for (int i = 1; i < 7; i++) if (blockIdx.x >= p.d[i].tile0) di = i;
    const TDesc dd = p.d[di];
    const int lt = blockIdx.x - dd.tile0;
    const int tilesX = (dd.C + 31) >> 5;
    const int c0 = (lt % tilesX) * 32, r0 = (lt / tilesX) * 32;
    const int tx = threadIdx.x, ty = threadIdx.y;   // (32, 8)
    #pragma unroll
    for (int j = 0; j < 4; j++) {
        const int rr = r0 + ty + j * 8;
        if (rr < dd.R && c0 + tx < dd.C)
            tile[ty + j * 8][tx] = dd.in[(size_t)rr * dd.C + c0 + tx];
    }
    __syncthreads();
    #pragma unroll
    for (int j = 0; j < 4; j++) {
        const int cc = c0 + ty + j * 8;
        const int kk = r0 + tx;
        if (cc < dd.C && kk < dd.R)
            dd.out[(size_t)cc * dd.ldout + dd.off + kk] = f2bs(tile[tx][ty + j * 8]);
    }
}

// wcat_t[768][6144]
__global__ void wcat_k(const float* __restrict__ cw, const float* __restrict__ gw,
                       ushort_t* __restrict__ out)
{
    int t = blockIdx.x * 256 + threadIdx.x;
    if (t >= DM * 8 * DM) return;
    const int o = t / (8 * DM);
    const int rr = t - o * 8 * DM;
    const int seg = rr / DM;
    const int i = rr - seg * DM;
    float v = (seg < 7) ? cw[(size_t)o * (DM * 7) + i * 7 + seg]
                        : gw[(size_t)i * DM + o];
    out[t] = f2bs(v);
}

// depthwise causal conv + bias + silu
__global__ void dwconv_k(const ushort_t* __restrict__ xz, const float* __restrict__ w,
                         const float* __restrict__ bcv, ushort_t* __restrict__ out)
{
    int t = blockIdx.x * 256 + threadIdx.x;
    if (t >= M_ROWS * DI) return;
    const int d = t % DI;
    const int bl = t / DI;
    const int l = bl & 511;
    const ushort_t* xp = xz + (size_t)bl * (2 * DI) + d;
    float s = bcv[d];
    #pragma unroll
    for (int k = 0; k < 4; k++) {
        const int ls = l + k - 3;
        if (ls >= 0) s += w[d * 4 + k] * us2f(xp[(ptrdiff_t)(k - 3) * (2 * DI)]);
    }
    out[t] = f2bs(s / (1.f + __expf(-s)));
}

// ---------------------------------------------------------------------------
// Segmented selective scan (unchanged from R8)
// ---------------------------------------------------------------------------
__global__ __launch_bounds__(256) void scan_a_k(
    const float* __restrict__ dtb, const ushort_t* __restrict__ xmc,
    const ushort_t* __restrict__ xdbl, const float* __restrict__ A_log,
    ushort_t* __restrict__ Aseg, float* __restrict__ Bseg)
{
    __shared__ ushort_t B_s[SL][16];
    const int tid = threadIdx.x;
    const int d   = blockIdx.x * 256 + tid;
    const int b   = blockIdx.y;
    const int sg  = blockIdx.z;
    const int l0  = sg * SL;

    const ushort_t* dbp = xdbl + ((size_t)b * LSEQ + l0) * 80;
    #pragma unroll
    for (int e = 0; e < 2; e++) {
        const int idx = tid + e * 256;
        const int ll = idx >> 4, n = idx & 15;
        B_s[ll][n] = dbp[(size_t)ll * 80 + DTRANK + n];
    }

    float Ad[16], h[16], Ap[16];
    #pragma unroll
    for (int n = 0; n < 16; n++) {
        Ad[n] = -__expf(A_log[(size_t)d * DSTATE + n]);
        h[n] = 0.f; Ap[n] = 1.f;
    }
    const float*    dtp = dtb + ((size_t)b * LSEQ + l0) * DI + d;
    const ushort_t* xp  = xmc + ((size_t)b * LSEQ + l0) * DI + d;
    __syncthreads();

    for (int l = 0; l < SL; ++l) {
        const float dtv = dtp[(size_t)l * DI];
        const float dx  = dtv * us2f(xp[(size_t)l * DI]);
        #pragma unroll
        for (int n = 0; n < 16; n++) {
            const float a = __expf(dtv * Ad[n]);
            h[n] = a * h[n] + us2f(B_s[l][n]) * dx;
            Ap[n] *= a;
        }
    }
    #pragma unroll
    for (int n = 0; n < 16; n++) {
        const size_t o = ((size_t)(b * SEG + sg) * 16 + n) * DI + d;
        Aseg[o] = f2bs(Ap[n]);
        Bseg[o] = h[n];
    }
}

__global__ __launch_bounds__(256) void scan_b_k(
    const float* __restrict__ dtb, ushort_t* __restrict__ xmc,
    const ushort_t* __restrict__ xdbl, const ushort_t* __restrict__ xz,
    const float* __restrict__ A_log, const float* __restrict__ Dp,
    const ushort_t* __restrict__ Aseg, const float* __restrict__ Bseg)
{
    __shared__ ushort_t B_s[SL][16];
    __shared__ ushort_t C_s[SL][16];
    const int tid = threadIdx.x;
    const int d   = blockIdx.x * 256 + tid;
    const int b   = blockIdx.y;
    const int sg  = blockIdx.z;
    const int l0  = sg * SL;

    const ushort_t* dbp = xdbl + ((size_t)b * LSEQ + l0) * 80;
    #pragma unroll
    for (int e = 0; e < 2; e++) {
        const int idx = tid + e * 256;
        const int ll = idx >> 4, n = idx & 15;
        B_s[ll][n] = dbp[(size_t)ll * 80 + DTRANK + n];
        C_s[ll][n] = dbp[(size_t)ll * 80 + DTRANK + DSTATE + n];
    }

    float Ad[16], h[16];
    #pragma unroll
    for (int n = 0; n < 16; n++) {
        Ad[n] = -__expf(A_log[(size_t)d * DSTATE + n]);
        h[n] = 0.f;
    }
    for (int s = 0; s < sg; ++s) {
        #pragma unroll
        for (int n = 0; n < 16; n++) {
            const size_t o = ((size_t)(b * SEG + s) * 16 + n) * DI + d;
            h[n] = us2f(Aseg[o]) * h[n] + Bseg[o];
        }
    }
    const float Dd = Dp[d];
    const float*    dtp = dtb + ((size_t)b * LSEQ + l0) * DI + d;
    ushort_t*       xp  = xmc + ((size_t)b * LSEQ + l0) * DI + d;
    const ushort_t* zp  = xz  + ((size_t)b * LSEQ + l0) * (2 * DI) + DI + d;
    __syncthreads();

    for (int l = 0; l < SL; ++l) {
        const float dtv = dtp[(size_t)l * DI];
        const float xv  = us2f(xp[(size_t)l * DI]);
        const float dx  = dtv * xv;
        float p = 0.f;
        #pragma unroll
        for (int n = 0; n < 16; n++) {
            const float a = __expf(dtv * Ad[n]);
            h[n] = a * h[n] + us2f(B_s[l][n]) * dx;
            p += h[n] * us2f(C_s[l][n]);
        }
        const float zv = us2f(zp[(size_t)l * 2 * DI]);
        const float sz = zv / (1.f + __expf(-zv));
        xp[(size_t)l * DI] = f2bs((p + Dd * xv) * sz);
    }
}

extern "C" void kernel_launch(void* const* d_in, const int* in_sizes, int n_in,
                              void* d_out, int out_size, void* d_ws, size_t ws_size,
                              hipStream_t stream)
{
    const float* x        = (const float*)d_in[0];
    const float* nv1      = (const float*)d_in[1];
    const float* nv2      = (const float*)d_in[2];
    const float* n1w      = (const float*)d_in[3];
    const float* n1b      = (const float*)d_in[4];
    const float* n2w      = (const float*)d_in[5];
    const float* n2b      = (const float*)d_in[6];
    const float* gcn_w    = (const float*)d_in[7];
    const float* gcn_b    = (const float*)d_in[8];
    const float* conv_w   = (const float*)d_in[9];
    const float* conv_b   = (const float*)d_in[10];
    const float* ggw      = (const float*)d_in[11];
    const float* ggb      = (const float*)d_in[12];
    const float* gmw      = (const float*)d_in[13];
    const float* gmb      = (const float*)d_in[14];
    const float* ow       = (const float*)d_in[15];
    const float* ob       = (const float*)d_in[16];
    const float* m_in_w   = (const float*)d_in[17];
    const float* m_conv_w = (const float*)d_in[18];
    const float* m_conv_b = (const float*)d_in[19];
    const float* m_xproj_w= (const float*)d_in[20];
    const float* m_dt_w   = (const float*)d_in[21];
    const float* m_dt_b   = (const float*)d_in[22];
    const float* m_A_log  = (const float*)d_in[23];
    const float* m_D      = (const float*)d_in[24];
    const float* m_out_w  = (const float*)d_in[25];

    float* out_main = (float*)d_out;
    float* out_adj  = out_main + (size_t)M_ROWS * DM;

    // workspace layout (~98.1 MB incl. zero page)
    ushort_t* wsb = (ushort_t*)d_ws;
    ushort_t* xn_bf   = wsb;                       //  3,145,728
    ushort_t* xz_bf   = xn_bf   + 3145728;         // 12,582,912
    ushort_t* xmc_bf  = xz_bf   + 12582912;        //  6,291,456 (y in place)
    ushort_t* xdbl_bf = xmc_bf  + 6291456;         //    327,680
    ushort_t* gcnmam  = xdbl_bf + 327680;          //  6,291,456 [xgcn|xmamba]
    ushort_t* wcat_t  = gcnmam  + 6291456;         //  4,718,592
    ushort_t* in_w_t  = wcat_t  + 4718592;         //  2,359,296
    ushort_t* xproj_t = in_w_t  + 2359296;         //    122,880
    ushort_t* dtw_t   = xproj_t + 122880;          //     73,728
    ushort_t* outw_t  = dtw_t   + 73728;           //  1,179,648
    ushort_t* gates_t = outw_t  + 1179648;         //  1,179,648
    ushort_t* ow_t    = gates_t + 1179648;         //    589,824
    float*    dtb     = (float*)(ow_t + 589824);   //  6,291,456 fp32
    ushort_t* zpage   = (ushort_t*)(dtb + 6291456);//  256 B zeroed
    // aliases
    ushort_t* fused   = xz_bf + 3145728;           // xz dead after scan
    float*    outtmp  = dtb;                       // dtb dead after scan
    float*    P1      = dtb;                       // conv split-K partials
    float*    P2      = (float*)wcat_t;            // xproj partials (pre-scan)
    ushort_t* Aseg    = xn_bf;                     // xn dead after in_proj
    float*    Bseg    = (float*)wcat_t;            // wcat+in_w dead after GEMMs

    const dim3 blk(256);
    const dim3 tblk(32, 8);

    hipMemsetAsync(zpage, 0, 256, stream);

    // ---- weight prep ----
    wcat_k<<<(DM * 8 * DM + 255) / 256, blk, 0, stream>>>(conv_w, gcn_w, wcat_t);
    TPack tp;
    int t0 = 0;
    auto fill = [&](int i, const float* in, ushort_t* out, int R, int C, int ldo, int off) {
        tp.d[i] = TDesc{in, out, R, C, ldo, off, t0};
        t0 += ((C + 31) / 32) * ((R + 31) / 32);
    };
    fill(0, m_in_w,    in_w_t,  768, 3072, 768, 0);
    fill(1, m_xproj_w, xproj_t, 1536, 80, 1536, 0);
    fill(2, m_dt_w,    dtw_t,   48, 1536, 48, 0);
    fill(3, m_out_w,   outw_t,  1536, 768, 1536, 0);
    fill(4, ggw,       gates_t, 768, 768, 1536, 0);
    fill(5, gmw,       gates_t, 768, 768, 1536, 768);
    fill(6, ow,        ow_t,    768, 768, 768, 0);
    tcvt7_k<<<t0, tblk, 0, stream>>>(tp);

    // ---- forward ----
    adj_k<<<16, blk, 0, stream>>>(nv1, nv2, out_adj);
    ln_k<<<M_ROWS, blk, 0, stream>>>(x, nullptr, n1w, n1b, nullptr, xn_bf);

    // x_gcn (+ conv over L): split-K=2 -> P1 -> combine -> gcnmam[:, 0:768]
    gemm_k<64, 64><<<dim3(64, 12, 2), blk, 0, stream>>>(
        xn_bf, DM, wcat_t, nullptr, nullptr, nullptr, nullptr, 0,
        DM, 8 * DM, FLAG_CONV, 48, P1, zpage, nullptr);
    combine_k<<<(M_ROWS * DM + 255) / 256, blk, 0, stream>>>(
        P1, 2, DM, conv_b, gcn_b, nullptr, gcnmam, 2 * DM, 0);
    // xz = xn @ m_in_w -> bf16 [4096][3072]
    gemm_k<64, 128><<<dim3(64, 24, 1), blk, 0, stream>>>(
        xn_bf, DM, in_w_t, nullptr, nullptr, nullptr, xz_bf, 2 * DI,
        2 * DI, DM, 0, 1 << 20, nullptr, zpage, nullptr);
    // xm = silu(dwconv(xm)) -> xmc bf16
    dwconv_k<<<(M_ROWS * DI + 255) / 256, blk, 0, stream>>>(xz_bf, m_conv_w, m_conv_b, xmc_bf);
    // x_dbl = xm @ m_xproj_w: split-K=4 -> P2 -> combine -> xdbl bf16
    gemm_k<64, 32><<<dim3(64, 3, 4), blk, 0, stream>>>(
        xmc_bf, DI, xproj_t, nullptr, nullptr, nullptr, nullptr, 0,
        80, DI, 0, 6, P2, zpage, nullptr);
    combine_k<<<(M_ROWS * 80 + 255) / 256, blk, 0, stream>>>(
        P2, 4, 80, nullptr, nullptr, nullptr, xdbl_bf, 80, 0);
    // dt = softplus(x_dbl[:, :48] @ m_dt_w + b) -> fp32
    gemm_k<64, 64><<<dim3(64, 24, 1), blk, 0, stream>>>(
        xdbl_bf, 80, dtw_t, m_dt_b, nullptr, dtb, nullptr, DI,
        DI, DTRANK, FLAG_SP, 1 << 20, nullptr, zpage, nullptr);
    // segmented selective scan -> y bf16 in place over xmc
    scan_a_k<<<dim3(DI / 256, B_SZ, SEG), blk, 0, stream>>>(
        dtb, xmc_bf, xdbl_bf, m_A_log, Aseg, Bseg);
    scan_b_k<<<dim3(DI / 256, B_SZ, SEG), blk, 0, stream>>>(
        dtb, xmc_bf, xdbl_bf, xz_bf, m_A_log, m_D, Aseg, Bseg);
    // x_mamba = y @ m_out_w -> gcnmam[:, 768:1536]
    gemm_k<64, 64><<<dim3(64, 12, 1), blk, 0, stream>>>(
        xmc_bf, DI, outw_t, nullptr, nullptr, nullptr, gcnmam + DM, 2 * DM,
        DM, DI, 0, 1 << 20, nullptr, zpage, nullptr);
    // gate GEMM + fused sigmoid blend epilogue -> fused bf16 (over dead xz)
    gemm_k<64, 64><<<dim3(64, 12, 1), blk, 0, stream>>>(
        gcnmam, 2 * DM, gates_t, ggb, gmb, nullptr, fused, DM,
        DM, 2 * DM, FLAG_FUSE, 1 << 20, nullptr, zpage, gcnmam);
    // out = fused @ out_w + ob -> fp32 (over dead dtb/P1)
    gemm_k<64, 64><<<dim3(64, 12, 1), blk, 0, stream>>>(
        fused, DM, ow_t, ob, nullptr, outtmp, nullptr, DM,
        DM, DM, 0, 1 << 20, nullptr, zpage, nullptr);
    // final LN2(outtmp + x) -> fp32 d_out
    ln_k<<<M_ROWS, blk, 0, stream>>>(outtmp, x, n2w, n2b, out_main, nullptr);
}

// Round 10
// 631.944 us; speedup vs baseline: 3.3990x; 1.0390x over previous
//
#include <hip/hip_runtime.h>
#include <math.h>

typedef unsigned short ushort_t;

#define B_SZ 8
#define LSEQ 512
#define DM 768
#define DI 1536
#define DSTATE 16
#define DTRANK 48
#define M_ROWS (B_SZ * LSEQ)   // 4096

#define FLAG_SP   1
#define FLAG_CONV 2
#define FLAG_FUSE 4

#define SEG 16
#define SL  32

using short8v = __attribute__((ext_vector_type(8))) short;
using float4v = __attribute__((ext_vector_type(4))) float;

#define AS1(p) ((const __attribute__((address_space(1))) void*)(p))
#define AS3(p) ((__attribute__((address_space(3))) void*)(p))

__device__ __forceinline__ float us2f(ushort_t u) {
    union { unsigned int i; float f; } cv; cv.i = ((unsigned int)u) << 16; return cv.f;
}
__device__ __forceinline__ ushort_t f2bs(float f) {
    union { float f; unsigned int u; } cv; cv.f = f;
    unsigned int r = cv.u + 0x7FFFu + ((cv.u >> 16) & 1u);   // RNE
    return (ushort_t)(r >> 16);
}

// ---------------------------------------------------------------------------
// MFMA GEMM with direct global->LDS (width=16) staging.
// C[4096][N] = A[4096][lda](bf16) @ Wt^T (+b1+b2); Wt is [N][K] bf16.
// TM=TN=128 instantiation = m97 geometry (4 waves x 64x64, 32 MFMA/wave/tile)
// -> halves memory requests per FLOP vs 64x64.
// ---------------------------------------------------------------------------
template <int TM, int TN>
__global__ __launch_bounds__(256) void gemm_k(
    const ushort_t* __restrict__ A, int lda,
    const ushort_t* __restrict__ Wt,
    const float* __restrict__ b1, const float* __restrict__ b2,
    float* __restrict__ Cf, ushort_t* __restrict__ Cb, int ldc,
    int N, int K, int flags, int ktiles_per_z, float* __restrict__ Part,
    const ushort_t* __restrict__ zpage, const ushort_t* __restrict__ Gm)
{
    constexpr int MF = TM / 32;
    constexpr int NF = TN / 32;
    constexpr int AI = TM / 32;      // A 16B-issues per wave
    constexpr int BI = TN / 32;
    __shared__ short Alds[8 * TM * 8];
    __shared__ short Blds[8 * TN * 8];

    const int tid  = threadIdx.x;
    const int wave = tid >> 6;
    const int lane = tid & 63;
    const int l16  = lane & 15;
    const int quad = lane >> 4;
    const int bm   = blockIdx.x * TM;
    const int bn   = blockIdx.y * TN;
    const int wm   = (wave & 1) * (TM / 2);
    const int wn   = (wave >> 1) * (TN / 2);

    float4v acc[MF][NF];
    #pragma unroll
    for (int i = 0; i < MF; i++)
        #pragma unroll
        for (int j = 0; j < NF; j++)
            acc[i][j] = (float4v){0.f, 0.f, 0.f, 0.f};

    const int nkt = (K + 63) >> 6;
    const int kt0 = blockIdx.z * ktiles_per_z;
    const int kt1 = min(nkt, kt0 + ktiles_per_z);
    for (int kt = kt0; kt < kt1; ++kt) {
        const int k0 = kt << 6;
        int koff = k0, sh = 0;
        if (flags & FLAG_CONV) {
            const int seg = kt / 12;
            koff = (kt - seg * 12) << 6;
            sh = (seg < 7) ? (seg - 3) : 0;
        }
        // A staging
        #pragma unroll
        for (int i = 0; i < AI; i++) {
            const int j = wave * AI + i;
            const int slot = j * 64 + lane;
            const int c = slot / TM, r = slot % TM;
            const int mg = bm + r;
            const ushort_t* gp = zpage;
            if (flags & FLAG_CONV) {
                const int ls = (mg & 511) + sh;
                if (ls >= 0 && ls < LSEQ)
                    gp = A + (size_t)((mg >> 9) * LSEQ + ls) * lda + koff + c * 8;
            } else {
                if (k0 + c * 8 < K)
                    gp = A + (size_t)mg * lda + k0 + c * 8;
            }
            __builtin_amdgcn_global_load_lds(AS1(gp), AS3(Alds + j * 512), 16, 0, 0);
        }
        // B staging
        #pragma unroll
        for (int i = 0; i < BI; i++) {
            const int j = wave * BI + i;
            const int slot = j * 64 + lane;
            const int c = slot / TN, r = slot % TN;
            const int ng = bn + r;
            const ushort_t* gp = zpage;
            if (ng < N && (k0 + c * 8) < K)
                gp = Wt + (size_t)ng * K + k0 + c * 8;
            __builtin_amdgcn_global_load_lds(AS1(gp), AS3(Blds + j * 512), 16, 0, 0);
        }
        __syncthreads();

        short8v a0[MF], a1[MF], b0[NF], b1v[NF];
        #pragma unroll
        for (int mi = 0; mi < MF; mi++) {
            const int ar = wm + mi * 16 + l16;
            a0[mi] = *(const short8v*)(Alds + ((size_t)quad * TM + ar) * 8);
            a1[mi] = *(const short8v*)(Alds + ((size_t)(4 + quad) * TM + ar) * 8);
        }
        #pragma unroll
        for (int ni = 0; ni < NF; ni++) {
            const int br = wn + ni * 16 + l16;
            b0[ni] = *(const short8v*)(Blds + ((size_t)quad * TN + br) * 8);
            b1v[ni] = *(const short8v*)(Blds + ((size_t)(4 + quad) * TN + br) * 8);
        }
        #pragma unroll
        for (int mi = 0; mi < MF; mi++)
            #pragma unroll
            for (int ni = 0; ni < NF; ni++) {
                acc[mi][ni] = __builtin_amdgcn_mfma_f32_16x16x32_bf16(
                    a0[mi], b0[ni], acc[mi][ni], 0, 0, 0);
                acc[mi][ni] = __builtin_amdgcn_mfma_f32_16x16x32_bf16(
                    a1[mi], b1v[ni], acc[mi][ni], 0, 0, 0);
            }
        __syncthreads();
    }

    if (Part) {
        float* P = Part + (size_t)blockIdx.z * M_ROWS * N;
        #pragma unroll
        for (int ni = 0; ni < NF; ni++) {
            const int col = bn + wn + ni * 16 + l16;
            if (col >= N) continue;
            #pragma unroll
            for (int mi = 0; mi < MF; mi++) {
                const int row0 = bm + wm + mi * 16 + quad * 4;
                #pragma unroll
                for (int r = 0; r < 4; r++)
                    P[(size_t)(row0 + r) * N + col] = acc[mi][ni][r];
            }
        }
        return;
    }

    #pragma unroll
    for (int ni = 0; ni < NF; ni++) {
        const int col = bn + wn + ni * 16 + l16;
        if (col >= N) continue;
        const float bias = (b1 ? b1[col] : 0.f) + (b2 ? b2[col] : 0.f);
        #pragma unroll
        for (int mi = 0; mi < MF; mi++) {
            const int row0 = bm + wm + mi * 16 + quad * 4;
            #pragma unroll
            for (int r = 0; r < 4; r++) {
                float v = acc[mi][ni][r] + bias;
                const int row = row0 + r;
                if (flags & FLAG_FUSE) {
                    const float g = 1.f / (1.f + __expf(-v));
                    const float xg = us2f(Gm[(size_t)row * (2 * DM) + col]);
                    const float xm = us2f(Gm[(size_t)row * (2 * DM) + DM + col]);
                    Cb[(size_t)row * ldc + col] = f2bs(g * xg + (1.f - g) * xm);
                    continue;
                }
                if (flags & FLAG_SP) v = (v > 20.f) ? v : log1pf(__expf(v));
                const size_t idx = (size_t)row * ldc + col;
                if (Cf) Cf[idx] = v;
                else    Cb[idx] = f2bs(v);
            }
        }
    }
}

// reduce split-K partials + bias (+softplus)
__global__ void combine_k(const float* __restrict__ Part, int nsplit, int N,
                          const float* __restrict__ b1, const float* __restrict__ b2,
                          float* __restrict__ Cf, ushort_t* __restrict__ Cb,
                          int ldc, int flags)
{
    int t = blockIdx.x * 256 + threadIdx.x;
    if (t >= M_ROWS * N) return;
    const int row = t / N, col = t - row * N;
    float v = 0.f;
    for (int s = 0; s < nsplit; s++) v += Part[(size_t)s * M_ROWS * N + t];
    if (b1) v += b1[col];
    if (b2) v += b2[col];
    if (flags & FLAG_SP) v = (v > 20.f) ? v : log1pf(__expf(v));
    const size_t idx = (size_t)row * ldc + col;
    if (Cf) Cf[idx] = v;
    else    Cb[idx] = f2bs(v);
}

// adj = sigmoid(nv1 @ nv2) * (1 - eye)  -> fp32
__global__ void adj_k(const float* __restrict__ nv1, const float* __restrict__ nv2,
                      float* __restrict__ out)
{
    int t = blockIdx.x * 256 + threadIdx.x;
    if (t >= 64 * 64) return;
    int i = t >> 6, j = t & 63;
    float s = 0.f;
    #pragma unroll
    for (int k = 0; k < 16; k++) s += nv1[i * 16 + k] * nv2[k * 64 + j];
    out[t] = (i == j) ? 0.f : 1.f / (1.f + __expf(-s));
}

// LayerNorm over last dim (768)
__global__ __launch_bounds__(256) void ln_k(
    const float* __restrict__ xin, const float* __restrict__ addf,
    const float* __restrict__ w, const float* __restrict__ bparam,
    float* __restrict__ outf, ushort_t* __restrict__ outb)
{
    const int r = blockIdx.x;
    const int tid = threadIdx.x;
    const size_t base = (size_t)r * DM;
    float v[3];
    float s = 0.f, ss = 0.f;
    #pragma unroll
    for (int j = 0; j < 3; j++) {
        const int c = tid + 256 * j;
        float vv = xin[base + c];
        if (addf) vv += addf[base + c];
        v[j] = vv; s += vv; ss += vv * vv;
    }
    #pragma unroll
    for (int o = 32; o > 0; o >>= 1) { s += __shfl_down(s, o); ss += __shfl_down(ss, o); }
    __shared__ float sw[4], ssw[4];
    __shared__ float mu_s, rs_s;
    const int wid = tid >> 6;
    if ((tid & 63) == 0) { sw[wid] = s; ssw[wid] = ss; }
    __syncthreads();
    if (tid == 0) {
        float st = 0.f, sst = 0.f;
        #pragma unroll
        for (int i = 0; i < 4; i++) { st += sw[i]; sst += ssw[i]; }
        const float mu = st / (float)DM;
        const float var = sst / (float)DM - mu * mu;
        mu_s = mu; rs_s = rsqrtf(fmaxf(var, 0.f) + 1e-5f);
    }
    __syncthreads();
    const float mu = mu_s, rs = rs_s;
    #pragma unroll
    for (int j = 0; j < 3; j++) {
        const int c = tid + 256 * j;
        const float o = (v[j] - mu) * rs * w[c] + bparam[c];
        if (outf) outf[base + c] = o;
        if (outb) outb[base + c] = f2bs(o);
    }
}

// batched tiled transpose+cvt: 7 descriptors, flat tile index
struct TDesc { const float* in; ushort_t* out; int R, C, ldout, off, tile0; };
struct TPack { TDesc d[7]; };
__global__ void tcvt7_k(TPack p)
{
    __shared__ float tile[32][33];
    int di = 0;
    #pragma unroll
    for (int i = 1; i < 7; i++) if (blockIdx.x >= p.d[i].tile0) di = i;
    const TDesc dd = p.d[di];
    const int lt = blockIdx.x - dd.tile0;
    const int tilesX = (dd.C + 31) >> 5;
    const int c0 = (lt % tilesX) * 32, r0 = (lt / tilesX) * 32;
    const int tx = threadIdx.x, ty = threadIdx.y;   // (32, 8)
    #pragma unroll
    for (int j = 0; j < 4; j++) {
        const int rr = r0 + ty + j * 8;
        if (rr < dd.R && c0 + tx < dd.C)
            tile[ty + j * 8][tx] = dd.in[(size_t)rr * dd.C + c0 + tx];
    }
    __syncthreads();
    #pragma unroll
    for (int j = 0; j < 4; j++) {
        const int cc = c0 + ty + j * 8;
        const int kk = r0 + tx;
        if (cc < dd.C && kk < dd.R)
            dd.out[(size_t)cc * dd.ldout + dd.off + kk] = f2bs(tile[tx][ty + j * 8]);
    }
}

// wcat_t[768][6144]
__global__ void wcat_k(const float* __restrict__ cw, const float* __restrict__ gw,
                       ushort_t* __restrict__ out)
{
    int t = blockIdx.x * 256 + threadIdx.x;
    if (t >= DM * 8 * DM) return;
    const int o = t / (8 * DM);
    const int rr = t - o * 8 * DM;
    const int seg = rr / DM;
    const int i = rr - seg * DM;
    float v = (seg < 7) ? cw[(size_t)o * (DM * 7) + i * 7 + seg]
                        : gw[(size_t)i * DM + o];
    out[t] = f2bs(v);
}

// depthwise causal conv + bias + silu
__global__ void dwconv_k(const ushort_t* __restrict__ xz, const float* __restrict__ w,
                         const float* __restrict__ bcv, ushort_t* __restrict__ out)
{
    int t = blockIdx.x * 256 + threadIdx.x;
    if (t >= M_ROWS * DI) return;
    const int d = t % DI;
    const int bl = t / DI;
    const int l = bl & 511;
    const ushort_t* xp = xz + (size_t)bl * (2 * DI) + d;
    float s = bcv[d];
    #pragma unroll
    for (int k = 0; k < 4; k++) {
        const int ls = l + k - 3;
        if (ls >= 0) s += w[d * 4 + k] * us2f(xp[(ptrdiff_t)(k - 3) * (2 * DI)]);
    }
    out[t] = f2bs(s / (1.f + __expf(-s)));
}

// ---------------------------------------------------------------------------
// Segmented selective scan (unchanged)
// ---------------------------------------------------------------------------
__global__ __launch_bounds__(256) void scan_a_k(
    const float* __restrict__ dtb, const ushort_t* __restrict__ xmc,
    const ushort_t* __restrict__ xdbl, const float* __restrict__ A_log,
    ushort_t* __restrict__ Aseg, float* __restrict__ Bseg)
{
    __shared__ ushort_t B_s[SL][16];
    const int tid = threadIdx.x;
    const int d   = blockIdx.x * 256 + tid;
    const int b   = blockIdx.y;
    const int sg  = blockIdx.z;
    const int l0  = sg * SL;

    const ushort_t* dbp = xdbl + ((size_t)b * LSEQ + l0) * 80;
    #pragma unroll
    for (int e = 0; e < 2; e++) {
        const int idx = tid + e * 256;
        const int ll = idx >> 4, n = idx & 15;
        B_s[ll][n] = dbp[(size_t)ll * 80 + DTRANK + n];
    }

    float Ad[16], h[16], Ap[16];
    #pragma unroll
    for (int n = 0; n < 16; n++) {
        Ad[n] = -__expf(A_log[(size_t)d * DSTATE + n]);
        h[n] = 0.f; Ap[n] = 1.f;
    }
    const float*    dtp = dtb + ((size_t)b * LSEQ + l0) * DI + d;
    const ushort_t* xp  = xmc + ((size_t)b * LSEQ + l0) * DI + d;
    __syncthreads();

    for (int l = 0; l < SL; ++l) {
        const float dtv = dtp[(size_t)l * DI];
        const float dx  = dtv * us2f(xp[(size_t)l * DI]);
        #pragma unroll
        for (int n = 0; n < 16; n++) {
            const float a = __expf(dtv * Ad[n]);
            h[n] = a * h[n] + us2f(B_s[l][n]) * dx;
            Ap[n] *= a;
        }
    }
    #pragma unroll
    for (int n = 0; n < 16; n++) {
        const size_t o = ((size_t)(b * SEG + sg) * 16 + n) * DI + d;
        Aseg[o] = f2bs(Ap[n]);
        Bseg[o] = h[n];
    }
}

__global__ __launch_bounds__(256) void scan_b_k(
    const float* __restrict__ dtb, ushort_t* __restrict__ xmc,
    const ushort_t* __restrict__ xdbl, const ushort_t* __restrict__ xz,
    const float* __restrict__ A_log, const float* __restrict__ Dp,
    const ushort_t* __restrict__ Aseg, const float* __restrict__ Bseg)
{
    __shared__ ushort_t B_s[SL][16];
    __shared__ ushort_t C_s[SL][16];
    const int tid = threadIdx.x;
    const int d   = blockIdx.x * 256 + tid;
    const int b   = blockIdx.y;
    const int sg  = blockIdx.z;
    const int l0  = sg * SL;

    const ushort_t* dbp = xdbl + ((size_t)b * LSEQ + l0) * 80;
    #pragma unroll
    for (int e = 0; e < 2; e++) {
        const int idx = tid + e * 256;
        const int ll = idx >> 4, n = idx & 15;
        B_s[ll][n] = dbp[(size_t)ll * 80 + DTRANK + n];
        C_s[ll][n] = dbp[(size_t)ll * 80 + DTRANK + DSTATE + n];
    }

    float Ad[16], h[16];
    #pragma unroll
    for (int n = 0; n < 16; n++) {
        Ad[n] = -__expf(A_log[(size_t)d * DSTATE + n]);
        h[n] = 0.f;
    }
    for (int s = 0; s < sg; ++s) {
        #pragma unroll
        for (int n = 0; n < 16; n++) {
            const size_t o = ((size_t)(b * SEG + s) * 16 + n) * DI + d;
            h[n] = us2f(Aseg[o]) * h[n] + Bseg[o];
        }
    }
    const float Dd = Dp[d];
    const float*    dtp = dtb + ((size_t)b * LSEQ + l0) * DI + d;
    ushort_t*       xp  = xmc + ((size_t)b * LSEQ + l0) * DI + d;
    const ushort_t* zp  = xz  + ((size_t)b * LSEQ + l0) * (2 * DI) + DI + d;
    __syncthreads();

    for (int l = 0; l < SL; ++l) {
        const float dtv = dtp[(size_t)l * DI];
        const float xv  = us2f(xp[(size_t)l * DI]);
        const float dx  = dtv * xv;
        float p = 0.f;
        #pragma unroll
        for (int n = 0; n < 16; n++) {
            const float a = __expf(dtv * Ad[n]);
            h[n] = a * h[n] + us2f(B_s[l][n]) * dx;
            p += h[n] * us2f(C_s[l][n]);
        }
        const float zv = us2f(zp[(size_t)l * 2 * DI]);
        const float sz = zv / (1.f + __expf(-zv));
        xp[(size_t)l * DI] = f2bs((p + Dd * xv) * sz);
    }
}

extern "C" void kernel_launch(void* const* d_in, const int* in_sizes, int n_in,
                              void* d_out, int out_size, void* d_ws, size_t ws_size,
                              hipStream_t stream)
{
    const float* x        = (const float*)d_in[0];
    const float* nv1      = (const float*)d_in[1];
    const float* nv2      = (const float*)d_in[2];
    const float* n1w      = (const float*)d_in[3];
    const float* n1b      = (const float*)d_in[4];
    const float* n2w      = (const float*)d_in[5];
    const float* n2b      = (const float*)d_in[6];
    const float* gcn_w    = (const float*)d_in[7];
    const float* gcn_b    = (const float*)d_in[8];
    const float* conv_w   = (const float*)d_in[9];
    const float* conv_b   = (const float*)d_in[10];
    const float* ggw      = (const float*)d_in[11];
    const float* ggb      = (const float*)d_in[12];
    const float* gmw      = (const float*)d_in[13];
    const float* gmb      = (const float*)d_in[14];
    const float* ow       = (const float*)d_in[15];
    const float* ob       = (const float*)d_in[16];
    const float* m_in_w   = (const float*)d_in[17];
    const float* m_conv_w = (const float*)d_in[18];
    const float* m_conv_b = (const float*)d_in[19];
    const float* m_xproj_w= (const float*)d_in[20];
    const float* m_dt_w   = (const float*)d_in[21];
    const float* m_dt_b   = (const float*)d_in[22];
    const float* m_A_log  = (const float*)d_in[23];
    const float* m_D      = (const float*)d_in[24];
    const float* m_out_w  = (const float*)d_in[25];

    float* out_main = (float*)d_out;
    float* out_adj  = out_main + (size_t)M_ROWS * DM;

    // workspace layout (~98.1 MB incl. zero page)
    ushort_t* wsb = (ushort_t*)d_ws;
    ushort_t* xn_bf   = wsb;                       //  3,145,728
    ushort_t* xz_bf   = xn_bf   + 3145728;         // 12,582,912
    ushort_t* xmc_bf  = xz_bf   + 12582912;        //  6,291,456 (y in place)
    ushort_t* xdbl_bf = xmc_bf  + 6291456;         //    327,680
    ushort_t* gcnmam  = xdbl_bf + 327680;          //  6,291,456 [xgcn|xmamba]
    ushort_t* wcat_t  = gcnmam  + 6291456;         //  4,718,592
    ushort_t* in_w_t  = wcat_t  + 4718592;         //  2,359,296
    ushort_t* xproj_t = in_w_t  + 2359296;         //    122,880
    ushort_t* dtw_t   = xproj_t + 122880;          //     73,728
    ushort_t* outw_t  = dtw_t   + 73728;           //  1,179,648
    ushort_t* gates_t = outw_t  + 1179648;         //  1,179,648
    ushort_t* ow_t    = gates_t + 1179648;         //    589,824
    float*    dtb     = (float*)(ow_t + 589824);   //  6,291,456 fp32
    ushort_t* zpage   = (ushort_t*)(dtb + 6291456);//  256 B zeroed
    // aliases
    ushort_t* fused   = xz_bf + 3145728;           // xz dead after scan
    float*    outtmp  = dtb;                       // dtb dead after scan
    float*    P1      = (float*)xz_bf;             // conv partials: 3x12.58MB = xz+xmc region (exact, dead pre-in_proj)
    float*    P2      = (float*)wcat_t;            // xproj partials (wcat dead)
    float*    P3      = dtb;                       // out_proj partials: 2x12.58MB (dtb dead post-scan)
    ushort_t* Aseg    = xn_bf;                     // xn dead after in_proj
    float*    Bseg    = (float*)wcat_t;            // wcat+in_w dead after GEMMs

    const dim3 blk(256);
    const dim3 tblk(32, 8);

    hipMemsetAsync(zpage, 0, 256, stream);

    // ---- weight prep ----
    wcat_k<<<(DM * 8 * DM + 255) / 256, blk, 0, stream>>>(conv_w, gcn_w, wcat_t);
    TPack tp;
    int t0 = 0;
    auto fill = [&](int i, const float* in, ushort_t* out, int R, int C, int ldo, int off) {
        tp.d[i] = TDesc{in, out, R, C, ldo, off, t0};
        t0 += ((C + 31) / 32) * ((R + 31) / 32);
    };
    fill(0, m_in_w,    in_w_t,  768, 3072, 768, 0);
    fill(1, m_xproj_w, xproj_t, 1536, 80, 1536, 0);
    fill(2, m_dt_w,    dtw_t,   48, 1536, 48, 0);
    fill(3, m_out_w,   outw_t,  1536, 768, 1536, 0);
    fill(4, ggw,       gates_t, 768, 768, 1536, 0);
    fill(5, gmw,       gates_t, 768, 768, 1536, 768);
    fill(6, ow,        ow_t,    768, 768, 768, 0);
    tcvt7_k<<<t0, tblk, 0, stream>>>(tp);

    // ---- forward ----
    adj_k<<<16, blk, 0, stream>>>(nv1, nv2, out_adj);
    ln_k<<<M_ROWS, blk, 0, stream>>>(x, nullptr, n1w, n1b, nullptr, xn_bf);

    // x_gcn (+ conv over L): 128-tile, split-K=3 -> P1 -> combine -> gcnmam[:, 0:768]
    gemm_k<128, 128><<<dim3(32, 6, 3), blk, 0, stream>>>(
        xn_bf, DM, wcat_t, nullptr, nullptr, nullptr, nullptr, 0,
        DM, 8 * DM, FLAG_CONV, 32, P1, zpage, nullptr);
    combine_k<<<(M_ROWS * DM + 255) / 256, blk, 0, stream>>>(
        P1, 3, DM, conv_b, gcn_b, nullptr, gcnmam, 2 * DM, 0);
    // xz = xn @ m_in_w -> bf16 [4096][3072]  (128-tile)
    gemm_k<128, 128><<<dim3(32, 24, 1), blk, 0, stream>>>(
        xn_bf, DM, in_w_t, nullptr, nullptr, nullptr, xz_bf, 2 * DI,
        2 * DI, DM, 0, 1 << 20, nullptr, zpage, nullptr);
    // xm = silu(dwconv(xm)) -> xmc bf16
    dwconv_k<<<(M_ROWS * DI + 255) / 256, blk, 0, stream>>>(xz_bf, m_conv_w, m_conv_b, xmc_bf);
    // x_dbl = xm @ m_xproj_w: split-K=4 -> P2 -> combine -> xdbl bf16
    gemm_k<64, 32><<<dim3(64, 3, 4), blk, 0, stream>>>(
        xmc_bf, DI, xproj_t, nullptr, nullptr, nullptr, nullptr, 0,
        80, DI, 0, 6, P2, zpage, nullptr);
    combine_k<<<(M_ROWS * 80 + 255) / 256, blk, 0, stream>>>(
        P2, 4, 80, nullptr, nullptr, nullptr, xdbl_bf, 80, 0);
    // dt = softplus(x_dbl[:, :48] @ m_dt_w + b) -> fp32
    gemm_k<64, 64><<<dim3(64, 24, 1), blk, 0, stream>>>(
        xdbl_bf, 80, dtw_t, m_dt_b, nullptr, dtb, nullptr, DI,
        DI, DTRANK, FLAG_SP, 1 << 20, nullptr, zpage, nullptr);
    // segmented selective scan -> y bf16 in place over xmc
    scan_a_k<<<dim3(DI / 256, B_SZ, SEG), blk, 0, stream>>>(
        dtb, xmc_bf, xdbl_bf, m_A_log, Aseg, Bseg);
    scan_b_k<<<dim3(DI / 256, B_SZ, SEG), blk, 0, stream>>>(
        dtb, xmc_bf, xdbl_bf, xz_bf, m_A_log, m_D, Aseg, Bseg);
    // x_mamba = y @ m_out_w: 128-tile split-K=2 -> P3 -> combine -> gcnmam[:, 768:]
    gemm_k<128, 128><<<dim3(32, 6, 2), blk, 0, stream>>>(
        xmc_bf, DI, outw_t, nullptr, nullptr, nullptr, nullptr, 0,
        DM, DI, 0, 12, P3, zpage, nullptr);
    combine_k<<<(M_ROWS * DM + 255) / 256, blk, 0, stream>>>(
        P3, 2, DM, nullptr, nullptr, nullptr, gcnmam + DM, 2 * DM, 0);
    // gate GEMM + fused sigmoid blend epilogue -> fused bf16 (over dead xz)
    gemm_k<64, 64><<<dim3(64, 12, 1), blk, 0, stream>>>(
        gcnmam, 2 * DM, gates_t, ggb, gmb, nullptr, fused, DM,
        DM, 2 * DM, FLAG_FUSE, 1 << 20, nullptr, zpage, gcnmam);
    // out = fused @ out_w + ob -> fp32 (dtb dead again after P3 combine)
    gemm_k<64, 64><<<dim3(64, 12, 1), blk, 0, stream>>>(
        fused, DM, ow_t, ob, nullptr, outtmp, nullptr, DM,
        DM, DM, 0, 1 << 20, nullptr, zpage, nullptr);
    // final LN2(outtmp + x) -> fp32 d_out
    ln_k<<<M_ROWS, blk, 0, stream>>>(outtmp, x, n2w, n2b, out_main, nullptr);
}